// Round 3
// baseline (319.251 us; speedup 1.0000x reference)
//
#include <hip/hip_runtime.h>

#define N_NODES 100000
#define F_IN 128
#define H1 64
#define H2 32
#define NCLS 10

#define BS_N 256                                   // nodes per bucket
#define NBUCK ((N_NODES + BS_N - 1) / BS_N)        // 391 buckets
#define LCAP 32                                    // LDS slots per bucket
#define MCAP 9216                                  // main entries per bucket (16-aligned fills only)
#define OVCAP 6144                                 // overflow entries per bucket
#define STCAP 9216                                 // build LDS stage: mean 8192, +11 sigma
#define BIN_WG 256                                 // bin workgroups (1/CU), 512 thr each

typedef _Float16 h2_t __attribute__((ext_vector_type(2)));
typedef _Float16 f16x8 __attribute__((ext_vector_type(8)));
typedef float f32x4 __attribute__((ext_vector_type(4)));

// v_dot2_f32_f16: acc += pair.lo*sel.lo + pair.hi*sel.hi — 1 instr, no unpack
__device__ __forceinline__ float fdot2u(unsigned int u, h2_t sel, float c) {
    return __builtin_amdgcn_fdot2(__builtin_bit_cast(h2_t, u), sel, c, false);
}
// accumulate 8 packed fp16 (uint4) into a[0..7] with 8 dot2
__device__ __forceinline__ void accd4(float* a, uint4 v, h2_t lo, h2_t hi) {
    a[0] = fdot2u(v.x, lo, a[0]); a[1] = fdot2u(v.x, hi, a[1]);
    a[2] = fdot2u(v.y, lo, a[2]); a[3] = fdot2u(v.y, hi, a[3]);
    a[4] = fdot2u(v.z, lo, a[4]); a[5] = fdot2u(v.z, hi, a[5]);
    a[6] = fdot2u(v.w, lo, a[6]); a[7] = fdot2u(v.w, hi, a[7]);
}
// pack 2 f32 -> fp16x2 dword (v_cvt_pkrtz_f16_f32, 1 instr)
__device__ __forceinline__ unsigned int pkh(float a, float b) {
    return __builtin_bit_cast(unsigned int, __builtin_amdgcn_cvt_pkrtz(a, b));
}

// ---------------------------------------------------------------- pass 1: LDS-staged binning
__global__ __launch_bounds__(512) void bin_kernel(const int* __restrict__ src,
                                                  const int* __restrict__ dst, int E,
                                                  unsigned int* __restrict__ gcur,
                                                  unsigned int* __restrict__ mainr,
                                                  unsigned int* __restrict__ ovcnt,
                                                  unsigned int* __restrict__ ovbuf) {
    __shared__ unsigned int buf[NBUCK][LCAP];   // 50.0 KB
    __shared__ int cnt[NBUCK];
    int tid = threadIdx.x;
    for (int b = tid; b < NBUCK; b += 512) cnt[b] = 0;

    int chunk = (E + gridDim.x - 1) / gridDim.x;
    int e_lo = blockIdx.x * chunk;
    int e_hi = min(e_lo + chunk, E);

    int d0 = 0, s0 = 0, d1 = 0, s1 = 0;
    {
        int ea = e_lo + tid, eb = e_lo + 512 + tid;
        if (ea < e_hi) { d0 = dst[ea]; s0 = src[ea]; }
        if (eb < e_hi) { d1 = dst[eb]; s1 = src[eb]; }
    }
    __syncthreads();

    for (int base = e_lo; base < e_hi; base += 1024) {
        if (base + tid < e_hi) {
            int b = d0 >> 8;
            unsigned int en = ((unsigned int)s0 << 8) | (unsigned int)(d0 & 255);
            int p = atomicAdd(&cnt[b], 1);
            if (p < LCAP) buf[b][p] = en;
            else {
                unsigned int op = atomicAdd(&ovcnt[b * 16], 1u);
                if (op < OVCAP) ovbuf[(size_t)b * OVCAP + op] = en;
            }
        }
        if (base + 512 + tid < e_hi) {
            int b = d1 >> 8;
            unsigned int en = ((unsigned int)s1 << 8) | (unsigned int)(d1 & 255);
            int p = atomicAdd(&cnt[b], 1);
            if (p < LCAP) buf[b][p] = en;
            else {
                unsigned int op = atomicAdd(&ovcnt[b * 16], 1u);
                if (op < OVCAP) ovbuf[(size_t)b * OVCAP + op] = en;
            }
        }
        __syncthreads();
        {
            int nb = base + 1024;
            int ea = nb + tid, eb = nb + 512 + tid;
            if (ea < e_hi) { d0 = dst[ea]; s0 = src[ea]; }
            if (eb < e_hi) { d1 = dst[eb]; s1 = src[eb]; }
        }
        for (int b = tid; b < NBUCK; b += 512) {
            int c = cnt[b]; if (c > LCAP) c = LCAP;
            int nf = c & ~15;
            if (nf) {
                unsigned int gb = atomicAdd(&gcur[b * 16], (unsigned int)nf);
                if (gb + (unsigned)nf <= MCAP) {
                    for (int k = 0; k < nf; k += 4) {
                        uint4 v = make_uint4(buf[b][k], buf[b][k + 1],
                                             buf[b][k + 2], buf[b][k + 3]);
                        *(uint4*)&mainr[(size_t)b * MCAP + gb + k] = v;
                    }
                } else {
                    unsigned int op = atomicAdd(&ovcnt[b * 16], (unsigned int)nf);
                    for (int k = 0; k < nf; ++k)
                        if (op + k < OVCAP) ovbuf[(size_t)b * OVCAP + op + k] = buf[b][k];
                }
                int rem = c - nf;
                for (int k = 0; k < rem; ++k) buf[b][k] = buf[b][nf + k];
                cnt[b] = rem;
            } else {
                cnt[b] = c;
            }
        }
        __syncthreads();
    }
    for (int b = tid; b < NBUCK; b += 512) {
        int c = cnt[b]; if (c > LCAP) c = LCAP;
        if (c) {
            unsigned int ob = atomicAdd(&ovcnt[b * 16], (unsigned int)c);
            for (int k = 0; k < c; ++k)
                if (ob + k < OVCAP) ovbuf[(size_t)b * OVCAP + ob + k] = buf[b][k];
        }
    }
}

// ---------------------------------------------------------------- pass 2: per-bucket local CSR build
__global__ __launch_bounds__(256) void build_kernel(const unsigned int* __restrict__ gcur,
                                                    unsigned int* __restrict__ mainr,
                                                    const unsigned int* __restrict__ ovcnt,
                                                    const unsigned int* __restrict__ ovbuf,
                                                    float* __restrict__ dinv,
                                                    int2* __restrict__ row_se) {
    __shared__ unsigned int stage[STCAP];   // 36 KB
    __shared__ int degl[BS_N];
    __shared__ int rs_l[BS_N];
    __shared__ int curl[BS_N];
    __shared__ int wtot[4];
    int b = blockIdx.x;
    int tid = threadIdx.x;

    int cm = (int)gcur[b * 16]; if (cm > MCAP) cm = MCAP;
    for (int i = tid; i < cm; i += 256) stage[i] = mainr[(size_t)b * MCAP + i];
    int co = (int)ovcnt[b * 16]; if (co > OVCAP) co = OVCAP;
    for (int i = tid; i < co; i += 256) {
        int p = cm + i;
        if (p < STCAP) stage[p] = ovbuf[(size_t)b * OVCAP + i];
    }
    int c = cm + co; if (c > STCAP) c = STCAP;
    degl[tid] = 0;
    __syncthreads();

    for (int i = tid; i < c; i += 256) atomicAdd(&degl[stage[i] & 255], 1);
    __syncthreads();

    int lane = tid & 63, w = tid >> 6;
    int d = degl[tid];
    int x = d;
    #pragma unroll
    for (int off = 1; off < 64; off <<= 1) {
        int y = __shfl_up(x, off);
        if (lane >= off) x += y;
    }
    if (lane == 63) wtot[w] = x;
    __syncthreads();
    int pbase = 0;
    #pragma unroll
    for (int k = 0; k < 4; ++k) if (k < w) pbase += wtot[k];
    rs_l[tid] = pbase + x - d;
    curl[tid] = 0;
    __syncthreads();

    size_t gbase = (size_t)b * MCAP;
    for (int i = tid; i < c; i += 256) {
        unsigned int en = stage[i];
        int dl = en & 255;
        int p = atomicAdd(&curl[dl], 1);
        mainr[gbase + rs_l[dl] + p] = en >> 8;
    }
    int node = b * BS_N + tid;
    if (node < N_NODES) {
        int deg = degl[tid];
        dinv[node] = rsqrtf((float)deg + 1.0f);
        int rs = (int)gbase + rs_l[tid];
        row_se[node] = make_int2(rs, rs + deg);
    }
}

// ---------------------------------------------------------------- GEMM 1: [N,128]@[128,64] -> fp16 (MFMA f16)
// 64 rows/block, 4 waves, each wave one 16-row stripe x 64 cols.
// A frag: row=lane&15, k=(lane>>4)*8+j (verified layout, m89/lab-notes);
// B frag: col=lane&15, same k; D: col=lane&15, row=(lane>>4)*4+reg.
__global__ __launch_bounds__(256) void gemm1_kernel(const float* __restrict__ X,
                                                    const float* __restrict__ W,
                                                    const float* __restrict__ dinv,
                                                    unsigned short* __restrict__ H) {
    __shared__ union {
        struct {
            _Float16 As[64][136];   // +8 pad: frag ds_read_b128 lands 2-way max (free)
            _Float16 Wf[16][64][8]; // B-frag order: Wf[kgrp][col][j] = W[kgrp*8+j][col]
        } s;
        _Float16 Hs[64][72];        // epilogue staging (overlaps As; 72 for 16B-aligned rows)
    } u;
    int r0 = blockIdx.x * 64;
    int tid = threadIdx.x;
    // stage A: 64x128 f32 -> f16 (RNE via cast)
    for (int i = tid; i < 2048; i += 256) {
        int row = i >> 5, k4 = i & 31;
        int grow = r0 + row;
        float4 v = (grow < N_NODES) ? ((const float4*)X)[(size_t)grow * 32 + k4]
                                    : make_float4(0.f, 0.f, 0.f, 0.f);
        _Float16 t4[4] = {(_Float16)v.x, (_Float16)v.y, (_Float16)v.z, (_Float16)v.w};
        *(uint2*)&u.s.As[row][k4 * 4] = *(uint2*)t4;
    }
    // stage W in B-fragment order (8192 elems, once per block)
    for (int i = tid; i < F_IN * H1; i += 256) {
        int k = i >> 6, col = i & 63;
        u.s.Wf[k >> 3][col][k & 7] = (_Float16)W[i];
    }
    __syncthreads();

    int lane = tid & 63, w = tid >> 6;
    int lr = lane & 15, lkg = lane >> 4;
    f32x4 acc[4] = {{0.f, 0.f, 0.f, 0.f}, {0.f, 0.f, 0.f, 0.f},
                    {0.f, 0.f, 0.f, 0.f}, {0.f, 0.f, 0.f, 0.f}};
    #pragma unroll
    for (int ks = 0; ks < 4; ++ks) {
        f16x8 a = *(const f16x8*)&u.s.As[w * 16 + lr][ks * 32 + lkg * 8];
        #pragma unroll
        for (int nt = 0; nt < 4; ++nt) {
            f16x8 bfr = *(const f16x8*)&u.s.Wf[ks * 4 + lkg][nt * 16 + lr][0];
            acc[nt] = __builtin_amdgcn_mfma_f32_16x16x32_f16(a, bfr, acc[nt], 0, 0, 0);
        }
    }
    __syncthreads();            // all frag reads done before Hs overwrites As
    float dv[4];
    #pragma unroll
    for (int q = 0; q < 4; ++q) {
        int grow = r0 + w * 16 + lkg * 4 + q;
        dv[q] = (grow < N_NODES) ? dinv[grow] : 0.f;
    }
    #pragma unroll
    for (int nt = 0; nt < 4; ++nt)
        #pragma unroll
        for (int q = 0; q < 4; ++q)
            u.Hs[w * 16 + lkg * 4 + q][nt * 16 + lr] = (_Float16)(acc[nt][q] * dv[q]);
    __syncthreads();
    // cooperative coalesced store: 64 rows x 128B
    for (int i = tid; i < 512; i += 256) {
        int row = i >> 3, seg = i & 7;
        int grow = r0 + row;
        if (grow < N_NODES)
            *(uint4*)&H[(size_t)grow * H1 + seg * 8] = *(const uint4*)&u.Hs[row][seg * 8];
    }
}

// ---------------------------------------------------------------- GEMM 2: [N,64]@[64,32] -> fp16, scaled by dinv
__global__ __launch_bounds__(256) void gemm2_kernel(const float* __restrict__ X,
                                                    const float* __restrict__ W,
                                                    const float* __restrict__ dinv,
                                                    unsigned short* __restrict__ H) {
    __shared__ float Xs[64][68];
    __shared__ float Ws[H1 * H2];
    int r0 = blockIdx.x * 64;
    const float4* W4 = (const float4*)W;
    float4* Ws4 = (float4*)Ws;
    for (int i = threadIdx.x; i < H1 * H2 / 4; i += 256) Ws4[i] = W4[i];
    for (int it = 0; it < 4; ++it) {
        int idx = threadIdx.x + it * 256;
        int r = idx >> 4, k4 = idx & 15;
        int row = r0 + r;
        float4 v = (row < N_NODES)
            ? ((const float4*)X)[(size_t)row * 16 + k4]
            : make_float4(0.f, 0.f, 0.f, 0.f);
        *(float4*)&Xs[r][k4 * 4] = v;
    }
    __syncthreads();
    int tx = threadIdx.x & 15;
    int ty = threadIdx.x >> 4;
    float acc[4][2] = {};
    #pragma unroll 8
    for (int k = 0; k < 64; ++k) {
        float2 wb = *(const float2*)&Ws[k * H2 + tx * 2];
        float xa0 = Xs[ty * 4 + 0][k];
        float xa1 = Xs[ty * 4 + 1][k];
        float xa2 = Xs[ty * 4 + 2][k];
        float xa3 = Xs[ty * 4 + 3][k];
        acc[0][0] += xa0 * wb.x; acc[0][1] += xa0 * wb.y;
        acc[1][0] += xa1 * wb.x; acc[1][1] += xa1 * wb.y;
        acc[2][0] += xa2 * wb.x; acc[2][1] += xa2 * wb.y;
        acc[3][0] += xa3 * wb.x; acc[3][1] += xa3 * wb.y;
    }
    #pragma unroll
    for (int i = 0; i < 4; ++i) {
        int row = r0 + ty * 4 + i;
        if (row < N_NODES) {
            float dv = dinv[row];
            *(unsigned int*)&H[(size_t)row * H2 + tx * 2] = pkh(acc[i][0] * dv, acc[i][1] * dv);
        }
    }
}

// ---------------------------------------------------------------- pull1: wave/node, 8 lanes/edge
__global__ __launch_bounds__(256) void pull1_kernel(const unsigned short* __restrict__ h,
                                                    const unsigned int* __restrict__ csr,
                                                    const int2* __restrict__ row_se,
                                                    const float* __restrict__ dinv,
                                                    const float* __restrict__ b,
                                                    float* __restrict__ xout) {
    int wave = (blockIdx.x * 256 + threadIdx.x) >> 6;   // grid is exact: 25000 blocks
    int lane = threadIdx.x & 63;
    int g = lane >> 3;
    int sub = lane & 7;
    int i = wave;
    int2 se = row_se[i];
    int e0 = se.x, e1 = se.y;
    int deg = e1 - e0;
    const h2_t selo = {(_Float16)1.0f, (_Float16)0.0f};
    const h2_t sehi = {(_Float16)0.0f, (_Float16)1.0f};
    float acc[8] = {};
    if (deg <= 48) {                    // ~99.7% of nodes
        int sidx = (int)csr[e0 + lane];
        int i0 = __shfl(sidx, g);
        int i1 = __shfl(sidx, 8 + g);
        int i2 = __shfl(sidx, 16 + g);
        int i3 = __shfl(sidx, 24 + g);
        int i4 = __shfl(sidx, 32 + g);
        int i5 = __shfl(sidx, 40 + g);
        bool p0 = (g < deg),      p1 = (8 + g < deg),  p2 = (16 + g < deg);
        bool p3 = (24 + g < deg), p4 = (32 + g < deg), p5 = (40 + g < deg);
        uint4 v0 = make_uint4(0u, 0u, 0u, 0u), v1 = v0, v2 = v0, v3 = v0, v4 = v0, v5 = v0;
        if (p0) v0 = *(const uint4*)&h[(size_t)i0 * H1 + sub * 8];
        if (p1) v1 = *(const uint4*)&h[(size_t)i1 * H1 + sub * 8];
        if (p2) v2 = *(const uint4*)&h[(size_t)i2 * H1 + sub * 8];
        if (p3) v3 = *(const uint4*)&h[(size_t)i3 * H1 + sub * 8];
        if (p4) v4 = *(const uint4*)&h[(size_t)i4 * H1 + sub * 8];
        if (p5) v5 = *(const uint4*)&h[(size_t)i5 * H1 + sub * 8];
        if (p0) accd4(acc, v0, selo, sehi);
        if (p1) accd4(acc, v1, selo, sehi);
        if (p2) accd4(acc, v2, selo, sehi);
        if (p3) accd4(acc, v3, selo, sehi);
        if (p4) accd4(acc, v4, selo, sehi);
        if (p5) accd4(acc, v5, selo, sehi);
    } else {                            // rare heavy rows
        int e = e0;
        for (; e + 16 <= e1; e += 16) {
            int s0 = csr[e + g];
            int s1 = csr[e + 8 + g];
            uint4 v0 = *(const uint4*)&h[(size_t)s0 * H1 + sub * 8];
            uint4 v1 = *(const uint4*)&h[(size_t)s1 * H1 + sub * 8];
            accd4(acc, v0, selo, sehi);
            accd4(acc, v1, selo, sehi);
        }
        if (e + 8 <= e1) {
            int s = csr[e + g];
            uint4 v = *(const uint4*)&h[(size_t)s * H1 + sub * 8];
            accd4(acc, v, selo, sehi);
            e += 8;
        }
        if (e < e1) {
            int idx = e + g;
            if (idx < e1) {
                int s = csr[idx];
                uint4 v = *(const uint4*)&h[(size_t)s * H1 + sub * 8];
                accd4(acc, v, selo, sehi);
            }
        }
    }
    #pragma unroll
    for (int m = 8; m < 64; m <<= 1) {
        #pragma unroll
        for (int j = 0; j < 8; ++j) acc[j] += __shfl_xor(acc[j], m);
    }
    if (g == 0) {                       // lanes 0..7 finalize features sub*8..+7
        float di = dinv[i];
        uint4 sv = *(const uint4*)&h[(size_t)i * H1 + sub * 8];   // self loop
        accd4(acc, sv, selo, sehi);
        float4 bb0 = *(const float4*)&b[sub * 8];
        float4 bb1 = *(const float4*)&b[sub * 8 + 4];
        float4 o0, o1;
        o0.x = fmaxf(di * acc[0] + bb0.x, 0.0f);
        o0.y = fmaxf(di * acc[1] + bb0.y, 0.0f);
        o0.z = fmaxf(di * acc[2] + bb0.z, 0.0f);
        o0.w = fmaxf(di * acc[3] + bb0.w, 0.0f);
        o1.x = fmaxf(di * acc[4] + bb1.x, 0.0f);
        o1.y = fmaxf(di * acc[5] + bb1.y, 0.0f);
        o1.z = fmaxf(di * acc[6] + bb1.z, 0.0f);
        o1.w = fmaxf(di * acc[7] + bb1.w, 0.0f);
        *(float4*)&xout[(size_t)i * H1 + sub * 8] = o0;
        *(float4*)&xout[(size_t)i * H1 + sub * 8 + 4] = o1;
    }
}

// ---------------------------------------------------------------- pull2: wave/node, 4 lanes/edge
// Fused classifier + log_softmax in the epilogue (x2 never materialized).
__global__ __launch_bounds__(256) void pull2_kernel(const unsigned short* __restrict__ h,
                                                    const unsigned int* __restrict__ csr,
                                                    const int2* __restrict__ row_se,
                                                    const float* __restrict__ dinv,
                                                    const float* __restrict__ b,
                                                    const float* __restrict__ Wc,
                                                    const float* __restrict__ bc,
                                                    float* __restrict__ out) {
    __shared__ float WsL[H2 * NCLS];
    __shared__ float bsL[NCLS];
    for (int idx = threadIdx.x; idx < H2 * NCLS; idx += 256) WsL[idx] = Wc[idx];
    if (threadIdx.x < NCLS) bsL[threadIdx.x] = bc[threadIdx.x];
    __syncthreads();

    int wave = (blockIdx.x * 256 + threadIdx.x) >> 6;
    int lane = threadIdx.x & 63;
    int g = lane >> 2;
    int sub = lane & 3;
    int i = wave;
    int2 se = row_se[i];
    int e0 = se.x, e1 = se.y;
    int deg = e1 - e0;
    const h2_t selo = {(_Float16)1.0f, (_Float16)0.0f};
    const h2_t sehi = {(_Float16)0.0f, (_Float16)1.0f};
    float acc[8] = {};
    if (deg <= 48) {
        int sidx = (int)csr[e0 + lane];
        int i0 = __shfl(sidx, g);
        int i1 = __shfl(sidx, 16 + g);
        int i2 = __shfl(sidx, 32 + g);
        bool p0 = (g < deg), p1 = (16 + g < deg), p2 = (32 + g < deg);
        uint4 v0 = make_uint4(0u, 0u, 0u, 0u), v1 = v0, v2 = v0;
        if (p0) v0 = *(const uint4*)&h[(size_t)i0 * H2 + sub * 8];
        if (p1) v1 = *(const uint4*)&h[(size_t)i1 * H2 + sub * 8];
        if (p2) v2 = *(const uint4*)&h[(size_t)i2 * H2 + sub * 8];
        if (p0) accd4(acc, v0, selo, sehi);
        if (p1) accd4(acc, v1, selo, sehi);
        if (p2) accd4(acc, v2, selo, sehi);
    } else {
        int e = e0;
        for (; e + 32 <= e1; e += 32) {
            int s0 = csr[e + g];
            int s1 = csr[e + 16 + g];
            uint4 v0 = *(const uint4*)&h[(size_t)s0 * H2 + sub * 8];
            uint4 v1 = *(const uint4*)&h[(size_t)s1 * H2 + sub * 8];
            accd4(acc, v0, selo, sehi);
            accd4(acc, v1, selo, sehi);
        }
        if (e + 16 <= e1) {
            int s = csr[e + g];
            uint4 v = *(const uint4*)&h[(size_t)s * H2 + sub * 8];
            accd4(acc, v, selo, sehi);
            e += 16;
        }
        if (e < e1) {
            int idx = e + g;
            if (idx < e1) {
                int s = csr[idx];
                uint4 v = *(const uint4*)&h[(size_t)s * H2 + sub * 8];
                accd4(acc, v, selo, sehi);
            }
        }
    }
    #pragma unroll
    for (int m = 4; m < 64; m <<= 1) {
        #pragma unroll
        for (int j = 0; j < 8; ++j) acc[j] += __shfl_xor(acc[j], m);
    }
    if (g == 0) {                       // lanes 0..3 hold features sub*8..+7
        float di = dinv[i];
        uint4 sv = *(const uint4*)&h[(size_t)i * H2 + sub * 8];   // self loop
        accd4(acc, sv, selo, sehi);
        float4 bb0 = *(const float4*)&b[sub * 8];
        float4 bb1 = *(const float4*)&b[sub * 8 + 4];
        float x[8];
        x[0] = fmaxf(di * acc[0] + bb0.x, 0.0f);
        x[1] = fmaxf(di * acc[1] + bb0.y, 0.0f);
        x[2] = fmaxf(di * acc[2] + bb0.z, 0.0f);
        x[3] = fmaxf(di * acc[3] + bb0.w, 0.0f);
        x[4] = fmaxf(di * acc[4] + bb1.x, 0.0f);
        x[5] = fmaxf(di * acc[5] + bb1.y, 0.0f);
        x[6] = fmaxf(di * acc[6] + bb1.z, 0.0f);
        x[7] = fmaxf(di * acc[7] + bb1.w, 0.0f);
        // partial logits over this lane's 8 features
        float lgt[NCLS];
        #pragma unroll
        for (int c2 = 0; c2 < NCLS; ++c2) {
            float a2 = 0.f;
            #pragma unroll
            for (int j = 0; j < 8; ++j) a2 += x[j] * WsL[(sub * 8 + j) * NCLS + c2];
            lgt[c2] = a2;
        }
        // reduce over lanes 0..3 (all active in this branch)
        #pragma unroll
        for (int c2 = 0; c2 < NCLS; ++c2) lgt[c2] += __shfl_xor(lgt[c2], 1);
        #pragma unroll
        for (int c2 = 0; c2 < NCLS; ++c2) lgt[c2] += __shfl_xor(lgt[c2], 2);
        if (sub == 0) {
            float m2 = -1e30f;
            #pragma unroll
            for (int c2 = 0; c2 < NCLS; ++c2) {
                lgt[c2] += bsL[c2];
                m2 = fmaxf(m2, lgt[c2]);
            }
            float s2 = 0.f;
            #pragma unroll
            for (int c2 = 0; c2 < NCLS; ++c2) s2 += expf(lgt[c2] - m2);
            float lse = m2 + logf(s2);
            float* op = &out[(size_t)i * NCLS];
            #pragma unroll
            for (int c2 = 0; c2 < NCLS; c2 += 2)
                *(float2*)&op[c2] = make_float2(lgt[c2] - lse, lgt[c2 + 1] - lse);
        }
    }
}

// ----------------------------------------------------------------
extern "C" void kernel_launch(void* const* d_in, const int* in_sizes, int n_in,
                              void* d_out, int out_size, void* d_ws, size_t ws_size,
                              hipStream_t stream) {
    const float* feature = (const float*)d_in[0];
    const int*   eidx    = (const int*)d_in[1];
    const float* W1      = (const float*)d_in[2];
    const float* b1      = (const float*)d_in[3];
    const float* W2      = (const float*)d_in[4];
    const float* b2      = (const float*)d_in[5];
    const float* Wc      = (const float*)d_in[6];
    const float* bc      = (const float*)d_in[7];
    float* out = (float*)d_out;

    const int E = in_sizes[1] / 2;
    const int* src = eidx;
    const int* dst = eidx + E;

    float*          ws        = (float*)d_ws;
    float*          dinv      = ws;
    int2*           row_se    = (int2*)(dinv + N_NODES);
    unsigned int*   gcur      = (unsigned int*)(row_se + N_NODES);
    unsigned int*   ovcnt     = gcur + (size_t)NBUCK * 16;
    unsigned int*   ovbuf     = ovcnt + (size_t)NBUCK * 16;
    unsigned int*   mainr     = ovbuf + (size_t)NBUCK * OVCAP;
    unsigned short* h1b       = (unsigned short*)(mainr + (size_t)NBUCK * MCAP);
    float*          x1        = (float*)(h1b + (size_t)N_NODES * H1);
    unsigned short* h2b       = h1b;                 // overlay: h1 dead after pull1

    // CSR build
    hipMemsetAsync(gcur, 0, (size_t)NBUCK * 32 * sizeof(unsigned int), stream);
    bin_kernel<<<BIN_WG, 512, 0, stream>>>(src, dst, E, gcur, mainr, ovcnt, ovbuf);
    build_kernel<<<NBUCK, 256, 0, stream>>>(gcur, mainr, ovcnt, ovbuf, dinv, row_se);

    // layer 1
    gemm1_kernel<<<(N_NODES + 63) / 64, 256, 0, stream>>>(feature, W1, dinv, h1b);
    {
        unsigned int grid = (unsigned int)(((size_t)N_NODES * 64 + 255) / 256);
        pull1_kernel<<<grid, 256, 0, stream>>>(h1b, mainr, row_se, dinv, b1, x1);
    }

    // layer 2 + fused classifier
    gemm2_kernel<<<(N_NODES + 63) / 64, 256, 0, stream>>>(x1, W2, dinv, h2b);
    {
        unsigned int grid = (unsigned int)(((size_t)N_NODES * 64 + 255) / 256);
        pull2_kernel<<<grid, 256, 0, stream>>>(h2b, mainr, row_se, dinv, b2, Wc, bc, out);
    }
}

// Round 4
// 288.039 us; speedup vs baseline: 1.1084x; 1.1084x over previous
//
#include <hip/hip_runtime.h>

#define N_NODES 100000
#define F_IN 128
#define H1 64
#define H2 32
#define NCLS 10

#define BS_N 256                                   // nodes per bucket
#define NBUCK ((N_NODES + BS_N - 1) / BS_N)        // 391 buckets
#define LCAP 32                                    // LDS slots per bucket
#define MCAP 9216                                  // main entries per bucket (16-aligned fills only)
#define OVCAP 6144                                 // overflow entries per bucket
#define STCAP 9216                                 // build LDS stage: mean 8192, +11 sigma
#define BIN_WG 256                                 // bin workgroups (1/CU), 512 thr each

typedef _Float16 h2_t __attribute__((ext_vector_type(2)));
typedef _Float16 f16x8 __attribute__((ext_vector_type(8)));
typedef float f32x4 __attribute__((ext_vector_type(4)));

// v_dot2_f32_f16: acc += pair.lo*sel.lo + pair.hi*sel.hi — 1 instr, no unpack
__device__ __forceinline__ float fdot2u(unsigned int u, h2_t sel, float c) {
    return __builtin_amdgcn_fdot2(__builtin_bit_cast(h2_t, u), sel, c, false);
}
// accumulate 8 packed fp16 (uint4) into a[0..7] with 8 dot2
__device__ __forceinline__ void accd4(float* a, uint4 v, h2_t lo, h2_t hi) {
    a[0] = fdot2u(v.x, lo, a[0]); a[1] = fdot2u(v.x, hi, a[1]);
    a[2] = fdot2u(v.y, lo, a[2]); a[3] = fdot2u(v.y, hi, a[3]);
    a[4] = fdot2u(v.z, lo, a[4]); a[5] = fdot2u(v.z, hi, a[5]);
    a[6] = fdot2u(v.w, lo, a[6]); a[7] = fdot2u(v.w, hi, a[7]);
}
// pack 2 f32 -> fp16x2 dword (v_cvt_pkrtz_f16_f32, 1 instr)
__device__ __forceinline__ unsigned int pkh(float a, float b) {
    return __builtin_bit_cast(unsigned int, __builtin_amdgcn_cvt_pkrtz(a, b));
}

// ---------------------------------------------------------------- pass 1: LDS-staged binning
__global__ __launch_bounds__(512) void bin_kernel(const int* __restrict__ src,
                                                  const int* __restrict__ dst, int E,
                                                  unsigned int* __restrict__ gcur,
                                                  unsigned int* __restrict__ mainr,
                                                  unsigned int* __restrict__ ovcnt,
                                                  unsigned int* __restrict__ ovbuf) {
    __shared__ unsigned int buf[NBUCK][LCAP];   // 50.0 KB
    __shared__ int cnt[NBUCK];
    int tid = threadIdx.x;
    for (int b = tid; b < NBUCK; b += 512) cnt[b] = 0;

    int chunk = (E + gridDim.x - 1) / gridDim.x;
    int e_lo = blockIdx.x * chunk;
    int e_hi = min(e_lo + chunk, E);

    int d0 = 0, s0 = 0, d1 = 0, s1 = 0;
    {
        int ea = e_lo + tid, eb = e_lo + 512 + tid;
        if (ea < e_hi) { d0 = dst[ea]; s0 = src[ea]; }
        if (eb < e_hi) { d1 = dst[eb]; s1 = src[eb]; }
    }
    __syncthreads();

    for (int base = e_lo; base < e_hi; base += 1024) {
        if (base + tid < e_hi) {
            int b = d0 >> 8;
            unsigned int en = ((unsigned int)s0 << 8) | (unsigned int)(d0 & 255);
            int p = atomicAdd(&cnt[b], 1);
            if (p < LCAP) buf[b][p] = en;
            else {
                unsigned int op = atomicAdd(&ovcnt[b * 16], 1u);
                if (op < OVCAP) ovbuf[(size_t)b * OVCAP + op] = en;
            }
        }
        if (base + 512 + tid < e_hi) {
            int b = d1 >> 8;
            unsigned int en = ((unsigned int)s1 << 8) | (unsigned int)(d1 & 255);
            int p = atomicAdd(&cnt[b], 1);
            if (p < LCAP) buf[b][p] = en;
            else {
                unsigned int op = atomicAdd(&ovcnt[b * 16], 1u);
                if (op < OVCAP) ovbuf[(size_t)b * OVCAP + op] = en;
            }
        }
        __syncthreads();
        {
            int nb = base + 1024;
            int ea = nb + tid, eb = nb + 512 + tid;
            if (ea < e_hi) { d0 = dst[ea]; s0 = src[ea]; }
            if (eb < e_hi) { d1 = dst[eb]; s1 = src[eb]; }
        }
        for (int b = tid; b < NBUCK; b += 512) {
            int c = cnt[b]; if (c > LCAP) c = LCAP;
            int nf = c & ~15;
            if (nf) {
                unsigned int gb = atomicAdd(&gcur[b * 16], (unsigned int)nf);
                if (gb + (unsigned)nf <= MCAP) {
                    for (int k = 0; k < nf; k += 4) {
                        uint4 v = make_uint4(buf[b][k], buf[b][k + 1],
                                             buf[b][k + 2], buf[b][k + 3]);
                        *(uint4*)&mainr[(size_t)b * MCAP + gb + k] = v;
                    }
                } else {
                    unsigned int op = atomicAdd(&ovcnt[b * 16], (unsigned int)nf);
                    for (int k = 0; k < nf; ++k)
                        if (op + k < OVCAP) ovbuf[(size_t)b * OVCAP + op + k] = buf[b][k];
                }
                int rem = c - nf;
                for (int k = 0; k < rem; ++k) buf[b][k] = buf[b][nf + k];
                cnt[b] = rem;
            } else {
                cnt[b] = c;
            }
        }
        __syncthreads();
    }
    for (int b = tid; b < NBUCK; b += 512) {
        int c = cnt[b]; if (c > LCAP) c = LCAP;
        if (c) {
            unsigned int ob = atomicAdd(&ovcnt[b * 16], (unsigned int)c);
            for (int k = 0; k < c; ++k)
                if (ob + k < OVCAP) ovbuf[(size_t)b * OVCAP + ob + k] = buf[b][k];
        }
    }
}

// ---------------------------------------------------------------- pass 2: per-bucket local CSR build
__global__ __launch_bounds__(256) void build_kernel(const unsigned int* __restrict__ gcur,
                                                    unsigned int* __restrict__ mainr,
                                                    const unsigned int* __restrict__ ovcnt,
                                                    const unsigned int* __restrict__ ovbuf,
                                                    float* __restrict__ dinv,
                                                    int2* __restrict__ row_se) {
    __shared__ unsigned int stage[STCAP];   // 36 KB
    __shared__ int degl[BS_N];
    __shared__ int rs_l[BS_N];
    __shared__ int curl[BS_N];
    __shared__ int wtot[4];
    int b = blockIdx.x;
    int tid = threadIdx.x;

    int cm = (int)gcur[b * 16]; if (cm > MCAP) cm = MCAP;
    for (int i = tid; i < cm; i += 256) stage[i] = mainr[(size_t)b * MCAP + i];
    int co = (int)ovcnt[b * 16]; if (co > OVCAP) co = OVCAP;
    for (int i = tid; i < co; i += 256) {
        int p = cm + i;
        if (p < STCAP) stage[p] = ovbuf[(size_t)b * OVCAP + i];
    }
    int c = cm + co; if (c > STCAP) c = STCAP;
    degl[tid] = 0;
    __syncthreads();

    for (int i = tid; i < c; i += 256) atomicAdd(&degl[stage[i] & 255], 1);
    __syncthreads();

    int lane = tid & 63, w = tid >> 6;
    int d = degl[tid];
    int x = d;
    #pragma unroll
    for (int off = 1; off < 64; off <<= 1) {
        int y = __shfl_up(x, off);
        if (lane >= off) x += y;
    }
    if (lane == 63) wtot[w] = x;
    __syncthreads();
    int pbase = 0;
    #pragma unroll
    for (int k = 0; k < 4; ++k) if (k < w) pbase += wtot[k];
    rs_l[tid] = pbase + x - d;
    curl[tid] = 0;
    __syncthreads();

    size_t gbase = (size_t)b * MCAP;
    for (int i = tid; i < c; i += 256) {
        unsigned int en = stage[i];
        int dl = en & 255;
        int p = atomicAdd(&curl[dl], 1);
        mainr[gbase + rs_l[dl] + p] = en >> 8;
    }
    int node = b * BS_N + tid;
    if (node < N_NODES) {
        int deg = degl[tid];
        dinv[node] = rsqrtf((float)deg + 1.0f);
        int rs = (int)gbase + rs_l[tid];
        row_se[node] = make_int2(rs, rs + deg);
    }
}

// ---------------------------------------------------------------- GEMM 1: [N,128]@[128,64] -> fp16 (MFMA f16)
// 64 rows/block, 4 waves, each wave one 16-row stripe x 64 cols.
__global__ __launch_bounds__(256) void gemm1_kernel(const float* __restrict__ X,
                                                    const float* __restrict__ W,
                                                    const float* __restrict__ dinv,
                                                    unsigned short* __restrict__ H) {
    __shared__ union {
        struct {
            _Float16 As[64][136];   // +8 pad: frag ds_read_b128 lands 2-way max (free)
            _Float16 Wf[16][64][8]; // B-frag order: Wf[kgrp][col][j] = W[kgrp*8+j][col]
        } s;
        _Float16 Hs[64][72];        // epilogue staging (overlaps As; 72 for 16B-aligned rows)
    } u;
    int r0 = blockIdx.x * 64;
    int tid = threadIdx.x;
    // stage A: 64x128 f32 -> f16 (RNE via cast)
    for (int i = tid; i < 2048; i += 256) {
        int row = i >> 5, k4 = i & 31;
        int grow = r0 + row;
        float4 v = (grow < N_NODES) ? ((const float4*)X)[(size_t)grow * 32 + k4]
                                    : make_float4(0.f, 0.f, 0.f, 0.f);
        _Float16 t4[4] = {(_Float16)v.x, (_Float16)v.y, (_Float16)v.z, (_Float16)v.w};
        *(uint2*)&u.s.As[row][k4 * 4] = *(uint2*)t4;
    }
    // stage W in B-fragment order (8192 elems, once per block)
    for (int i = tid; i < F_IN * H1; i += 256) {
        int k = i >> 6, col = i & 63;
        u.s.Wf[k >> 3][col][k & 7] = (_Float16)W[i];
    }
    __syncthreads();

    int lane = tid & 63, w = tid >> 6;
    int lr = lane & 15, lkg = lane >> 4;
    f32x4 acc[4] = {{0.f, 0.f, 0.f, 0.f}, {0.f, 0.f, 0.f, 0.f},
                    {0.f, 0.f, 0.f, 0.f}, {0.f, 0.f, 0.f, 0.f}};
    #pragma unroll
    for (int ks = 0; ks < 4; ++ks) {
        f16x8 a = *(const f16x8*)&u.s.As[w * 16 + lr][ks * 32 + lkg * 8];
        #pragma unroll
        for (int nt = 0; nt < 4; ++nt) {
            f16x8 bfr = *(const f16x8*)&u.s.Wf[ks * 4 + lkg][nt * 16 + lr][0];
            acc[nt] = __builtin_amdgcn_mfma_f32_16x16x32_f16(a, bfr, acc[nt], 0, 0, 0);
        }
    }
    __syncthreads();            // all frag reads done before Hs overwrites As
    float dv[4];
    #pragma unroll
    for (int q = 0; q < 4; ++q) {
        int grow = r0 + w * 16 + lkg * 4 + q;
        dv[q] = (grow < N_NODES) ? dinv[grow] : 0.f;
    }
    #pragma unroll
    for (int nt = 0; nt < 4; ++nt)
        #pragma unroll
        for (int q = 0; q < 4; ++q)
            u.Hs[w * 16 + lkg * 4 + q][nt * 16 + lr] = (_Float16)(acc[nt][q] * dv[q]);
    __syncthreads();
    // cooperative coalesced store: 64 rows x 128B
    for (int i = tid; i < 512; i += 256) {
        int row = i >> 3, seg = i & 7;
        int grow = r0 + row;
        if (grow < N_NODES)
            *(uint4*)&H[(size_t)grow * H1 + seg * 8] = *(const uint4*)&u.Hs[row][seg * 8];
    }
}

// ---------------------------------------------------------------- GEMM 2: [N,64]@[64,32] -> fp16, scaled by dinv
__global__ __launch_bounds__(256) void gemm2_kernel(const float* __restrict__ X,
                                                    const float* __restrict__ W,
                                                    const float* __restrict__ dinv,
                                                    unsigned short* __restrict__ H) {
    __shared__ float Xs[64][68];
    __shared__ float Ws[H1 * H2];
    int r0 = blockIdx.x * 64;
    const float4* W4 = (const float4*)W;
    float4* Ws4 = (float4*)Ws;
    for (int i = threadIdx.x; i < H1 * H2 / 4; i += 256) Ws4[i] = W4[i];
    for (int it = 0; it < 4; ++it) {
        int idx = threadIdx.x + it * 256;
        int r = idx >> 4, k4 = idx & 15;
        int row = r0 + r;
        float4 v = (row < N_NODES)
            ? ((const float4*)X)[(size_t)row * 16 + k4]
            : make_float4(0.f, 0.f, 0.f, 0.f);
        *(float4*)&Xs[r][k4 * 4] = v;
    }
    __syncthreads();
    int tx = threadIdx.x & 15;
    int ty = threadIdx.x >> 4;
    float acc[4][2] = {};
    #pragma unroll 8
    for (int k = 0; k < 64; ++k) {
        float2 wb = *(const float2*)&Ws[k * H2 + tx * 2];
        float xa0 = Xs[ty * 4 + 0][k];
        float xa1 = Xs[ty * 4 + 1][k];
        float xa2 = Xs[ty * 4 + 2][k];
        float xa3 = Xs[ty * 4 + 3][k];
        acc[0][0] += xa0 * wb.x; acc[0][1] += xa0 * wb.y;
        acc[1][0] += xa1 * wb.x; acc[1][1] += xa1 * wb.y;
        acc[2][0] += xa2 * wb.x; acc[2][1] += xa2 * wb.y;
        acc[3][0] += xa3 * wb.x; acc[3][1] += xa3 * wb.y;
    }
    #pragma unroll
    for (int i = 0; i < 4; ++i) {
        int row = r0 + ty * 4 + i;
        if (row < N_NODES) {
            float dv = dinv[row];
            *(unsigned int*)&H[(size_t)row * H2 + tx * 2] = pkh(acc[i][0] * dv, acc[i][1] * dv);
        }
    }
}

// ---------------------------------------------------------------- pull1: wave/node, 8 lanes/edge
__global__ __launch_bounds__(256) void pull1_kernel(const unsigned short* __restrict__ h,
                                                    const unsigned int* __restrict__ csr,
                                                    const int2* __restrict__ row_se,
                                                    const float* __restrict__ dinv,
                                                    const float* __restrict__ b,
                                                    float* __restrict__ xout) {
    int wave = (blockIdx.x * 256 + threadIdx.x) >> 6;   // grid is exact: 25000 blocks
    int lane = threadIdx.x & 63;
    int g = lane >> 3;
    int sub = lane & 7;
    int i = wave;
    int2 se = row_se[i];
    int e0 = se.x, e1 = se.y;
    int deg = e1 - e0;
    const h2_t selo = {(_Float16)1.0f, (_Float16)0.0f};
    const h2_t sehi = {(_Float16)0.0f, (_Float16)1.0f};
    float acc[8] = {};
    if (deg <= 48) {                    // ~99.7% of nodes
        int sidx = (int)csr[e0 + lane];
        int i0 = __shfl(sidx, g);
        int i1 = __shfl(sidx, 8 + g);
        int i2 = __shfl(sidx, 16 + g);
        int i3 = __shfl(sidx, 24 + g);
        int i4 = __shfl(sidx, 32 + g);
        int i5 = __shfl(sidx, 40 + g);
        bool p0 = (g < deg),      p1 = (8 + g < deg),  p2 = (16 + g < deg);
        bool p3 = (24 + g < deg), p4 = (32 + g < deg), p5 = (40 + g < deg);
        uint4 v0 = make_uint4(0u, 0u, 0u, 0u), v1 = v0, v2 = v0, v3 = v0, v4 = v0, v5 = v0;
        if (p0) v0 = *(const uint4*)&h[(size_t)i0 * H1 + sub * 8];
        if (p1) v1 = *(const uint4*)&h[(size_t)i1 * H1 + sub * 8];
        if (p2) v2 = *(const uint4*)&h[(size_t)i2 * H1 + sub * 8];
        if (p3) v3 = *(const uint4*)&h[(size_t)i3 * H1 + sub * 8];
        if (p4) v4 = *(const uint4*)&h[(size_t)i4 * H1 + sub * 8];
        if (p5) v5 = *(const uint4*)&h[(size_t)i5 * H1 + sub * 8];
        if (p0) accd4(acc, v0, selo, sehi);
        if (p1) accd4(acc, v1, selo, sehi);
        if (p2) accd4(acc, v2, selo, sehi);
        if (p3) accd4(acc, v3, selo, sehi);
        if (p4) accd4(acc, v4, selo, sehi);
        if (p5) accd4(acc, v5, selo, sehi);
    } else {                            // rare heavy rows
        int e = e0;
        for (; e + 16 <= e1; e += 16) {
            int s0 = csr[e + g];
            int s1 = csr[e + 8 + g];
            uint4 v0 = *(const uint4*)&h[(size_t)s0 * H1 + sub * 8];
            uint4 v1 = *(const uint4*)&h[(size_t)s1 * H1 + sub * 8];
            accd4(acc, v0, selo, sehi);
            accd4(acc, v1, selo, sehi);
        }
        if (e + 8 <= e1) {
            int s = csr[e + g];
            uint4 v = *(const uint4*)&h[(size_t)s * H1 + sub * 8];
            accd4(acc, v, selo, sehi);
            e += 8;
        }
        if (e < e1) {
            int idx = e + g;
            if (idx < e1) {
                int s = csr[idx];
                uint4 v = *(const uint4*)&h[(size_t)s * H1 + sub * 8];
                accd4(acc, v, selo, sehi);
            }
        }
    }
    #pragma unroll
    for (int m = 8; m < 64; m <<= 1) {
        #pragma unroll
        for (int j = 0; j < 8; ++j) acc[j] += __shfl_xor(acc[j], m);
    }
    if (g == 0) {                       // lanes 0..7 finalize features sub*8..+7
        float di = dinv[i];
        uint4 sv = *(const uint4*)&h[(size_t)i * H1 + sub * 8];   // self loop
        accd4(acc, sv, selo, sehi);
        float4 bb0 = *(const float4*)&b[sub * 8];
        float4 bb1 = *(const float4*)&b[sub * 8 + 4];
        float4 o0, o1;
        o0.x = fmaxf(di * acc[0] + bb0.x, 0.0f);
        o0.y = fmaxf(di * acc[1] + bb0.y, 0.0f);
        o0.z = fmaxf(di * acc[2] + bb0.z, 0.0f);
        o0.w = fmaxf(di * acc[3] + bb0.w, 0.0f);
        o1.x = fmaxf(di * acc[4] + bb1.x, 0.0f);
        o1.y = fmaxf(di * acc[5] + bb1.y, 0.0f);
        o1.z = fmaxf(di * acc[6] + bb1.z, 0.0f);
        o1.w = fmaxf(di * acc[7] + bb1.w, 0.0f);
        *(float4*)&xout[(size_t)i * H1 + sub * 8] = o0;
        *(float4*)&xout[(size_t)i * H1 + sub * 8 + 4] = o1;
    }
}

// ---------------------------------------------------------------- pull2: wave/node, 4 lanes/edge
__global__ __launch_bounds__(256) void pull2_kernel(const unsigned short* __restrict__ h,
                                                    const unsigned int* __restrict__ csr,
                                                    const int2* __restrict__ row_se,
                                                    const float* __restrict__ dinv,
                                                    const float* __restrict__ b,
                                                    float* __restrict__ xout) {
    int wave = (blockIdx.x * 256 + threadIdx.x) >> 6;
    int lane = threadIdx.x & 63;
    int g = lane >> 2;
    int sub = lane & 3;
    int i = wave;
    int2 se = row_se[i];
    int e0 = se.x, e1 = se.y;
    int deg = e1 - e0;
    const h2_t selo = {(_Float16)1.0f, (_Float16)0.0f};
    const h2_t sehi = {(_Float16)0.0f, (_Float16)1.0f};
    float acc[8] = {};
    if (deg <= 48) {
        int sidx = (int)csr[e0 + lane];
        int i0 = __shfl(sidx, g);
        int i1 = __shfl(sidx, 16 + g);
        int i2 = __shfl(sidx, 32 + g);
        bool p0 = (g < deg), p1 = (16 + g < deg), p2 = (32 + g < deg);
        uint4 v0 = make_uint4(0u, 0u, 0u, 0u), v1 = v0, v2 = v0;
        if (p0) v0 = *(const uint4*)&h[(size_t)i0 * H2 + sub * 8];
        if (p1) v1 = *(const uint4*)&h[(size_t)i1 * H2 + sub * 8];
        if (p2) v2 = *(const uint4*)&h[(size_t)i2 * H2 + sub * 8];
        if (p0) accd4(acc, v0, selo, sehi);
        if (p1) accd4(acc, v1, selo, sehi);
        if (p2) accd4(acc, v2, selo, sehi);
    } else {
        int e = e0;
        for (; e + 32 <= e1; e += 32) {
            int s0 = csr[e + g];
            int s1 = csr[e + 16 + g];
            uint4 v0 = *(const uint4*)&h[(size_t)s0 * H2 + sub * 8];
            uint4 v1 = *(const uint4*)&h[(size_t)s1 * H2 + sub * 8];
            accd4(acc, v0, selo, sehi);
            accd4(acc, v1, selo, sehi);
        }
        if (e + 16 <= e1) {
            int s = csr[e + g];
            uint4 v = *(const uint4*)&h[(size_t)s * H2 + sub * 8];
            accd4(acc, v, selo, sehi);
            e += 16;
        }
        if (e < e1) {
            int idx = e + g;
            if (idx < e1) {
                int s = csr[idx];
                uint4 v = *(const uint4*)&h[(size_t)s * H2 + sub * 8];
                accd4(acc, v, selo, sehi);
            }
        }
    }
    #pragma unroll
    for (int m = 4; m < 64; m <<= 1) {
        #pragma unroll
        for (int j = 0; j < 8; ++j) acc[j] += __shfl_xor(acc[j], m);
    }
    if (g == 0) {                       // lanes 0..3 finalize
        float di = dinv[i];
        uint4 sv = *(const uint4*)&h[(size_t)i * H2 + sub * 8];   // self loop
        accd4(acc, sv, selo, sehi);
        float4 bb0 = *(const float4*)&b[sub * 8];
        float4 bb1 = *(const float4*)&b[sub * 8 + 4];
        float4 o0, o1;
        o0.x = fmaxf(di * acc[0] + bb0.x, 0.0f);
        o0.y = fmaxf(di * acc[1] + bb0.y, 0.0f);
        o0.z = fmaxf(di * acc[2] + bb0.z, 0.0f);
        o0.w = fmaxf(di * acc[3] + bb0.w, 0.0f);
        o1.x = fmaxf(di * acc[4] + bb1.x, 0.0f);
        o1.y = fmaxf(di * acc[5] + bb1.y, 0.0f);
        o1.z = fmaxf(di * acc[6] + bb1.z, 0.0f);
        o1.w = fmaxf(di * acc[7] + bb1.w, 0.0f);
        *(float4*)&xout[(size_t)i * H2 + sub * 8] = o0;
        *(float4*)&xout[(size_t)i * H2 + sub * 8 + 4] = o1;
    }
}

// ---------------------------------------------------------------- classifier + log_softmax
__global__ __launch_bounds__(256) void final_kernel(const float* __restrict__ X2,
                                                    const float* __restrict__ Wc,
                                                    const float* __restrict__ bc,
                                                    float* __restrict__ out) {
    __shared__ float Ws[H2 * NCLS];   // 320 floats > 256 threads: loop
    __shared__ float bs[NCLS];
    for (int idx = threadIdx.x; idx < H2 * NCLS; idx += 256) Ws[idx] = Wc[idx];
    if (threadIdx.x < NCLS) bs[threadIdx.x] = bc[threadIdx.x];
    __syncthreads();
    int i = blockIdx.x * blockDim.x + threadIdx.x;
    if (i >= N_NODES) return;
    float x[H2];
    #pragma unroll
    for (int k = 0; k < H2; ++k) x[k] = X2[(size_t)i * H2 + k];
    float lg[NCLS];
    #pragma unroll
    for (int c = 0; c < NCLS; ++c) {
        float acc = bs[c];
        #pragma unroll
        for (int k = 0; k < H2; ++k) acc += x[k] * Ws[k * NCLS + c];
        lg[c] = acc;
    }
    float m = lg[0];
    #pragma unroll
    for (int c = 1; c < NCLS; ++c) m = fmaxf(m, lg[c]);
    float s = 0.0f;
    #pragma unroll
    for (int c = 0; c < NCLS; ++c) s += expf(lg[c] - m);
    float lse = m + logf(s);
    #pragma unroll
    for (int c = 0; c < NCLS; ++c) out[(size_t)i * NCLS + c] = lg[c] - lse;
}

// ----------------------------------------------------------------
extern "C" void kernel_launch(void* const* d_in, const int* in_sizes, int n_in,
                              void* d_out, int out_size, void* d_ws, size_t ws_size,
                              hipStream_t stream) {
    const float* feature = (const float*)d_in[0];
    const int*   eidx    = (const int*)d_in[1];
    const float* W1      = (const float*)d_in[2];
    const float* b1      = (const float*)d_in[3];
    const float* W2      = (const float*)d_in[4];
    const float* b2      = (const float*)d_in[5];
    const float* Wc      = (const float*)d_in[6];
    const float* bc      = (const float*)d_in[7];
    float* out = (float*)d_out;

    const int E = in_sizes[1] / 2;
    const int* src = eidx;
    const int* dst = eidx + E;

    float*          ws        = (float*)d_ws;
    float*          dinv      = ws;
    int2*           row_se    = (int2*)(dinv + N_NODES);
    unsigned int*   gcur      = (unsigned int*)(row_se + N_NODES);
    unsigned int*   ovcnt     = gcur + (size_t)NBUCK * 16;
    unsigned int*   ovbuf     = ovcnt + (size_t)NBUCK * 16;
    unsigned int*   mainr     = ovbuf + (size_t)NBUCK * OVCAP;
    unsigned short* h1b       = (unsigned short*)(mainr + (size_t)NBUCK * MCAP);
    float*          x1        = (float*)(h1b + (size_t)N_NODES * H1);
    unsigned short* h2b       = h1b;                 // overlay: h1 dead after pull1
    float*          x2        = x1;                  // overlay: x1 dead after gemm2

    // CSR build
    hipMemsetAsync(gcur, 0, (size_t)NBUCK * 32 * sizeof(unsigned int), stream);
    bin_kernel<<<BIN_WG, 512, 0, stream>>>(src, dst, E, gcur, mainr, ovcnt, ovbuf);
    build_kernel<<<NBUCK, 256, 0, stream>>>(gcur, mainr, ovcnt, ovbuf, dinv, row_se);

    // layer 1
    gemm1_kernel<<<(N_NODES + 63) / 64, 256, 0, stream>>>(feature, W1, dinv, h1b);
    {
        unsigned int grid = (unsigned int)(((size_t)N_NODES * 64 + 255) / 256);
        pull1_kernel<<<grid, 256, 0, stream>>>(h1b, mainr, row_se, dinv, b1, x1);
    }

    // layer 2
    gemm2_kernel<<<(N_NODES + 63) / 64, 256, 0, stream>>>(x1, W2, dinv, h2b);
    {
        unsigned int grid = (unsigned int)(((size_t)N_NODES * 64 + 255) / 256);
        pull2_kernel<<<grid, 256, 0, stream>>>(h2b, mainr, row_se, dinv, b2, x2);
    }

    // classifier + log_softmax
    final_kernel<<<(N_NODES + 255) / 256, 256, 0, stream>>>(x2, Wc, bc, out);
}

// Round 5
// 275.058 us; speedup vs baseline: 1.1607x; 1.0472x over previous
//
#include <hip/hip_runtime.h>

#define N_NODES 100000
#define F_IN 128
#define H1 64
#define H2 32
#define NCLS 10

#define BS_N 256                                   // nodes per bucket
#define NBUCK ((N_NODES + BS_N - 1) / BS_N)        // 391 buckets
#define LCAP 32                                    // LDS slots per bucket
#define MCAP 9216                                  // main entries per bucket (16-aligned fills only)
#define OVCAP 6144                                 // overflow entries per bucket
#define STCAP 9216                                 // build LDS stage: mean 8192, +11 sigma
#define BIN_WG 256                                 // bin workgroups (1/CU), 512 thr each

typedef _Float16 h2_t __attribute__((ext_vector_type(2)));
typedef _Float16 f16x8 __attribute__((ext_vector_type(8)));
typedef float f32x4 __attribute__((ext_vector_type(4)));

// v_dot2_f32_f16: acc += pair.lo*sel.lo + pair.hi*sel.hi — 1 instr, no unpack
__device__ __forceinline__ float fdot2u(unsigned int u, h2_t sel, float c) {
    return __builtin_amdgcn_fdot2(__builtin_bit_cast(h2_t, u), sel, c, false);
}
// accumulate 8 packed fp16 (uint4) into a[0..7] with 8 dot2
__device__ __forceinline__ void accd4(float* a, uint4 v, h2_t lo, h2_t hi) {
    a[0] = fdot2u(v.x, lo, a[0]); a[1] = fdot2u(v.x, hi, a[1]);
    a[2] = fdot2u(v.y, lo, a[2]); a[3] = fdot2u(v.y, hi, a[3]);
    a[4] = fdot2u(v.z, lo, a[4]); a[5] = fdot2u(v.z, hi, a[5]);
    a[6] = fdot2u(v.w, lo, a[6]); a[7] = fdot2u(v.w, hi, a[7]);
}
// pack 2 f32 -> fp16x2 dword (v_cvt_pkrtz_f16_f32, 1 instr)
__device__ __forceinline__ unsigned int pkh(float a, float b) {
    return __builtin_bit_cast(unsigned int, __builtin_amdgcn_cvt_pkrtz(a, b));
}

// ---------------------------------------------------------------- pass 1: LDS-staged binning
__global__ __launch_bounds__(512) void bin_kernel(const int* __restrict__ src,
                                                  const int* __restrict__ dst, int E,
                                                  unsigned int* __restrict__ gcur,
                                                  unsigned int* __restrict__ mainr,
                                                  unsigned int* __restrict__ ovcnt,
                                                  unsigned int* __restrict__ ovbuf) {
    __shared__ unsigned int buf[NBUCK][LCAP];   // 50.0 KB
    __shared__ int cnt[NBUCK];
    int tid = threadIdx.x;
    for (int b = tid; b < NBUCK; b += 512) cnt[b] = 0;

    int chunk = (E + gridDim.x - 1) / gridDim.x;
    int e_lo = blockIdx.x * chunk;
    int e_hi = min(e_lo + chunk, E);

    int d0 = 0, s0 = 0, d1 = 0, s1 = 0;
    {
        int ea = e_lo + tid, eb = e_lo + 512 + tid;
        if (ea < e_hi) { d0 = dst[ea]; s0 = src[ea]; }
        if (eb < e_hi) { d1 = dst[eb]; s1 = src[eb]; }
    }
    __syncthreads();

    for (int base = e_lo; base < e_hi; base += 1024) {
        if (base + tid < e_hi) {
            int b = d0 >> 8;
            unsigned int en = ((unsigned int)s0 << 8) | (unsigned int)(d0 & 255);
            int p = atomicAdd(&cnt[b], 1);
            if (p < LCAP) buf[b][p] = en;
            else {
                unsigned int op = atomicAdd(&ovcnt[b * 16], 1u);
                if (op < OVCAP) ovbuf[(size_t)b * OVCAP + op] = en;
            }
        }
        if (base + 512 + tid < e_hi) {
            int b = d1 >> 8;
            unsigned int en = ((unsigned int)s1 << 8) | (unsigned int)(d1 & 255);
            int p = atomicAdd(&cnt[b], 1);
            if (p < LCAP) buf[b][p] = en;
            else {
                unsigned int op = atomicAdd(&ovcnt[b * 16], 1u);
                if (op < OVCAP) ovbuf[(size_t)b * OVCAP + op] = en;
            }
        }
        __syncthreads();
        {
            int nb = base + 1024;
            int ea = nb + tid, eb = nb + 512 + tid;
            if (ea < e_hi) { d0 = dst[ea]; s0 = src[ea]; }
            if (eb < e_hi) { d1 = dst[eb]; s1 = src[eb]; }
        }
        for (int b = tid; b < NBUCK; b += 512) {
            int c = cnt[b]; if (c > LCAP) c = LCAP;
            int nf = c & ~15;
            if (nf) {
                unsigned int gb = atomicAdd(&gcur[b * 16], (unsigned int)nf);
                if (gb + (unsigned)nf <= MCAP) {
                    for (int k = 0; k < nf; k += 4) {
                        uint4 v = make_uint4(buf[b][k], buf[b][k + 1],
                                             buf[b][k + 2], buf[b][k + 3]);
                        *(uint4*)&mainr[(size_t)b * MCAP + gb + k] = v;
                    }
                } else {
                    unsigned int op = atomicAdd(&ovcnt[b * 16], (unsigned int)nf);
                    for (int k = 0; k < nf; ++k)
                        if (op + k < OVCAP) ovbuf[(size_t)b * OVCAP + op + k] = buf[b][k];
                }
                int rem = c - nf;
                for (int k = 0; k < rem; ++k) buf[b][k] = buf[b][nf + k];
                cnt[b] = rem;
            } else {
                cnt[b] = c;
            }
        }
        __syncthreads();
    }
    for (int b = tid; b < NBUCK; b += 512) {
        int c = cnt[b]; if (c > LCAP) c = LCAP;
        if (c) {
            unsigned int ob = atomicAdd(&ovcnt[b * 16], (unsigned int)c);
            for (int k = 0; k < c; ++k)
                if (ob + k < OVCAP) ovbuf[(size_t)b * OVCAP + ob + k] = buf[b][k];
        }
    }
}

// ---------------------------------------------------------------- pass 2: per-bucket local CSR build
// Permute into LDS, then coalesced block-copy to global (was: 3.2M scattered
// global dword writes — same transaction class that bounds the pull kernels).
__global__ __launch_bounds__(512) void build_kernel(const unsigned int* __restrict__ gcur,
                                                    unsigned int* __restrict__ mainr,
                                                    const unsigned int* __restrict__ ovcnt,
                                                    const unsigned int* __restrict__ ovbuf,
                                                    float* __restrict__ dinv,
                                                    int2* __restrict__ row_se) {
    __shared__ unsigned int stage[STCAP];   // 36 KB
    __shared__ unsigned int outb[STCAP];    // 36 KB — permuted entries staged in LDS
    __shared__ int degl[BS_N];
    __shared__ int rs_l[BS_N];
    __shared__ int curl[BS_N];
    __shared__ int wtot[4];
    int b = blockIdx.x;
    int tid = threadIdx.x;

    int cm = (int)gcur[b * 16]; if (cm > MCAP) cm = MCAP;
    for (int i = tid; i < cm; i += 512) stage[i] = mainr[(size_t)b * MCAP + i];
    int co = (int)ovcnt[b * 16]; if (co > OVCAP) co = OVCAP;
    for (int i = tid; i < co; i += 512) {
        int p = cm + i;
        if (p < STCAP) stage[p] = ovbuf[(size_t)b * OVCAP + i];
    }
    int c = cm + co; if (c > STCAP) c = STCAP;
    if (tid < BS_N) degl[tid] = 0;
    __syncthreads();

    for (int i = tid; i < c; i += 512) atomicAdd(&degl[stage[i] & 255], 1);
    __syncthreads();

    if (tid < BS_N) {                       // exclusive scan over 256 degrees (4 waves)
        int lane = tid & 63, w = tid >> 6;
        int d = degl[tid];
        int x = d;
        #pragma unroll
        for (int off = 1; off < 64; off <<= 1) {
            int y = __shfl_up(x, off);
            if (lane >= off) x += y;
        }
        if (lane == 63) wtot[w] = x;
        __syncthreads();
        int pbase = 0;
        #pragma unroll
        for (int k = 0; k < 4; ++k) if (k < w) pbase += wtot[k];
        rs_l[tid] = pbase + x - d;
        curl[tid] = 0;
    } else {
        __syncthreads();                    // match the scan's inner barrier
    }
    __syncthreads();

    // permute into LDS (scattered 4B LDS writes: cheap) ...
    for (int i = tid; i < c; i += 512) {
        unsigned int en = stage[i];
        int dl = en & 255;
        int p = atomicAdd(&curl[dl], 1);
        outb[rs_l[dl] + p] = en >> 8;
    }
    __syncthreads();
    // ... then stream to global coalesced (uint4); over-copy to c+3 is safe (<= MCAP region)
    size_t gbase = (size_t)b * MCAP;
    int c4 = (c + 3) >> 2;
    for (int i = tid; i < c4; i += 512)
        *(uint4*)&mainr[gbase + (size_t)i * 4] = *(const uint4*)&outb[i * 4];

    int node = b * BS_N + tid;
    if (tid < BS_N && node < N_NODES) {
        int deg = degl[tid];
        dinv[node] = rsqrtf((float)deg + 1.0f);
        int rs = (int)gbase + rs_l[tid];
        row_se[node] = make_int2(rs, rs + deg);
    }
}

// ---------------------------------------------------------------- GEMM 1: [N,128]@[128,64] -> fp16 (MFMA f16)
__global__ __launch_bounds__(256) void gemm1_kernel(const float* __restrict__ X,
                                                    const float* __restrict__ W,
                                                    const float* __restrict__ dinv,
                                                    unsigned short* __restrict__ H) {
    __shared__ union {
        struct {
            _Float16 As[64][136];   // +8 pad: frag ds_read_b128 lands 2-way max (free)
            _Float16 Wf[16][64][8]; // B-frag order: Wf[kgrp][col][j] = W[kgrp*8+j][col]
        } s;
        _Float16 Hs[64][72];        // epilogue staging (overlaps As; 72 for 16B-aligned rows)
    } u;
    int r0 = blockIdx.x * 64;
    int tid = threadIdx.x;
    // stage A: 64x128 f32 -> f16 (RNE via cast)
    for (int i = tid; i < 2048; i += 256) {
        int row = i >> 5, k4 = i & 31;
        int grow = r0 + row;
        float4 v = (grow < N_NODES) ? ((const float4*)X)[(size_t)grow * 32 + k4]
                                    : make_float4(0.f, 0.f, 0.f, 0.f);
        _Float16 t4[4] = {(_Float16)v.x, (_Float16)v.y, (_Float16)v.z, (_Float16)v.w};
        *(uint2*)&u.s.As[row][k4 * 4] = *(uint2*)t4;
    }
    // stage W in B-fragment order (8192 elems, once per block)
    for (int i = tid; i < F_IN * H1; i += 256) {
        int k = i >> 6, col = i & 63;
        u.s.Wf[k >> 3][col][k & 7] = (_Float16)W[i];
    }
    __syncthreads();

    int lane = tid & 63, w = tid >> 6;
    int lr = lane & 15, lkg = lane >> 4;
    f32x4 acc[4] = {{0.f, 0.f, 0.f, 0.f}, {0.f, 0.f, 0.f, 0.f},
                    {0.f, 0.f, 0.f, 0.f}, {0.f, 0.f, 0.f, 0.f}};
    #pragma unroll
    for (int ks = 0; ks < 4; ++ks) {
        f16x8 a = *(const f16x8*)&u.s.As[w * 16 + lr][ks * 32 + lkg * 8];
        #pragma unroll
        for (int nt = 0; nt < 4; ++nt) {
            f16x8 bfr = *(const f16x8*)&u.s.Wf[ks * 4 + lkg][nt * 16 + lr][0];
            acc[nt] = __builtin_amdgcn_mfma_f32_16x16x32_f16(a, bfr, acc[nt], 0, 0, 0);
        }
    }
    __syncthreads();            // all frag reads done before Hs overwrites As
    float dv[4];
    #pragma unroll
    for (int q = 0; q < 4; ++q) {
        int grow = r0 + w * 16 + lkg * 4 + q;
        dv[q] = (grow < N_NODES) ? dinv[grow] : 0.f;
    }
    #pragma unroll
    for (int nt = 0; nt < 4; ++nt)
        #pragma unroll
        for (int q = 0; q < 4; ++q)
            u.Hs[w * 16 + lkg * 4 + q][nt * 16 + lr] = (_Float16)(acc[nt][q] * dv[q]);
    __syncthreads();
    // cooperative coalesced store: 64 rows x 128B
    for (int i = tid; i < 512; i += 256) {
        int row = i >> 3, seg = i & 7;
        int grow = r0 + row;
        if (grow < N_NODES)
            *(uint4*)&H[(size_t)grow * H1 + seg * 8] = *(const uint4*)&u.Hs[row][seg * 8];
    }
}

// ---------------------------------------------------------------- GEMM 2: [N,64]@[64,32] -> fp16, scaled by dinv
__global__ __launch_bounds__(256) void gemm2_kernel(const float* __restrict__ X,
                                                    const float* __restrict__ W,
                                                    const float* __restrict__ dinv,
                                                    unsigned short* __restrict__ H) {
    __shared__ float Xs[64][68];
    __shared__ float Ws[H1 * H2];
    int r0 = blockIdx.x * 64;
    const float4* W4 = (const float4*)W;
    float4* Ws4 = (float4*)Ws;
    for (int i = threadIdx.x; i < H1 * H2 / 4; i += 256) Ws4[i] = W4[i];
    for (int it = 0; it < 4; ++it) {
        int idx = threadIdx.x + it * 256;
        int r = idx >> 4, k4 = idx & 15;
        int row = r0 + r;
        float4 v = (row < N_NODES)
            ? ((const float4*)X)[(size_t)row * 16 + k4]
            : make_float4(0.f, 0.f, 0.f, 0.f);
        *(float4*)&Xs[r][k4 * 4] = v;
    }
    __syncthreads();
    int tx = threadIdx.x & 15;
    int ty = threadIdx.x >> 4;
    float acc[4][2] = {};
    #pragma unroll 8
    for (int k = 0; k < 64; ++k) {
        float2 wb = *(const float2*)&Ws[k * H2 + tx * 2];
        float xa0 = Xs[ty * 4 + 0][k];
        float xa1 = Xs[ty * 4 + 1][k];
        float xa2 = Xs[ty * 4 + 2][k];
        float xa3 = Xs[ty * 4 + 3][k];
        acc[0][0] += xa0 * wb.x; acc[0][1] += xa0 * wb.y;
        acc[1][0] += xa1 * wb.x; acc[1][1] += xa1 * wb.y;
        acc[2][0] += xa2 * wb.x; acc[2][1] += xa2 * wb.y;
        acc[3][0] += xa3 * wb.x; acc[3][1] += xa3 * wb.y;
    }
    #pragma unroll
    for (int i = 0; i < 4; ++i) {
        int row = r0 + ty * 4 + i;
        if (row < N_NODES) {
            float dv = dinv[row];
            *(unsigned int*)&H[(size_t)row * H2 + tx * 2] = pkh(acc[i][0] * dv, acc[i][1] * dv);
        }
    }
}

// ---------------------------------------------------------------- pull1: wave/node, 8 lanes/edge
__global__ __launch_bounds__(256) void pull1_kernel(const unsigned short* __restrict__ h,
                                                    const unsigned int* __restrict__ csr,
                                                    const int2* __restrict__ row_se,
                                                    const float* __restrict__ dinv,
                                                    const float* __restrict__ b,
                                                    float* __restrict__ xout) {
    int wave = (blockIdx.x * 256 + threadIdx.x) >> 6;   // grid is exact: 25000 blocks
    int lane = threadIdx.x & 63;
    int g = lane >> 3;
    int sub = lane & 7;
    int i = wave;
    int2 se = row_se[i];
    int e0 = se.x, e1 = se.y;
    int deg = e1 - e0;
    const h2_t selo = {(_Float16)1.0f, (_Float16)0.0f};
    const h2_t sehi = {(_Float16)0.0f, (_Float16)1.0f};
    float acc[8] = {};
    if (deg <= 48) {                    // ~99.7% of nodes
        int sidx = (int)csr[e0 + lane];
        int i0 = __shfl(sidx, g);
        int i1 = __shfl(sidx, 8 + g);
        int i2 = __shfl(sidx, 16 + g);
        int i3 = __shfl(sidx, 24 + g);
        int i4 = __shfl(sidx, 32 + g);
        int i5 = __shfl(sidx, 40 + g);
        bool p0 = (g < deg),      p1 = (8 + g < deg),  p2 = (16 + g < deg);
        bool p3 = (24 + g < deg), p4 = (32 + g < deg), p5 = (40 + g < deg);
        uint4 v0 = make_uint4(0u, 0u, 0u, 0u), v1 = v0, v2 = v0, v3 = v0, v4 = v0, v5 = v0;
        if (p0) v0 = *(const uint4*)&h[(size_t)i0 * H1 + sub * 8];
        if (p1) v1 = *(const uint4*)&h[(size_t)i1 * H1 + sub * 8];
        if (p2) v2 = *(const uint4*)&h[(size_t)i2 * H1 + sub * 8];
        if (p3) v3 = *(const uint4*)&h[(size_t)i3 * H1 + sub * 8];
        if (p4) v4 = *(const uint4*)&h[(size_t)i4 * H1 + sub * 8];
        if (p5) v5 = *(const uint4*)&h[(size_t)i5 * H1 + sub * 8];
        if (p0) accd4(acc, v0, selo, sehi);
        if (p1) accd4(acc, v1, selo, sehi);
        if (p2) accd4(acc, v2, selo, sehi);
        if (p3) accd4(acc, v3, selo, sehi);
        if (p4) accd4(acc, v4, selo, sehi);
        if (p5) accd4(acc, v5, selo, sehi);
    } else {                            // rare heavy rows
        int e = e0;
        for (; e + 16 <= e1; e += 16) {
            int s0 = csr[e + g];
            int s1 = csr[e + 8 + g];
            uint4 v0 = *(const uint4*)&h[(size_t)s0 * H1 + sub * 8];
            uint4 v1 = *(const uint4*)&h[(size_t)s1 * H1 + sub * 8];
            accd4(acc, v0, selo, sehi);
            accd4(acc, v1, selo, sehi);
        }
        if (e + 8 <= e1) {
            int s = csr[e + g];
            uint4 v = *(const uint4*)&h[(size_t)s * H1 + sub * 8];
            accd4(acc, v, selo, sehi);
            e += 8;
        }
        if (e < e1) {
            int idx = e + g;
            if (idx < e1) {
                int s = csr[idx];
                uint4 v = *(const uint4*)&h[(size_t)s * H1 + sub * 8];
                accd4(acc, v, selo, sehi);
            }
        }
    }
    #pragma unroll
    for (int m = 8; m < 64; m <<= 1) {
        #pragma unroll
        for (int j = 0; j < 8; ++j) acc[j] += __shfl_xor(acc[j], m);
    }
    if (g == 0) {                       // lanes 0..7 finalize features sub*8..+7
        float di = dinv[i];
        uint4 sv = *(const uint4*)&h[(size_t)i * H1 + sub * 8];   // self loop
        accd4(acc, sv, selo, sehi);
        float4 bb0 = *(const float4*)&b[sub * 8];
        float4 bb1 = *(const float4*)&b[sub * 8 + 4];
        float4 o0, o1;
        o0.x = fmaxf(di * acc[0] + bb0.x, 0.0f);
        o0.y = fmaxf(di * acc[1] + bb0.y, 0.0f);
        o0.z = fmaxf(di * acc[2] + bb0.z, 0.0f);
        o0.w = fmaxf(di * acc[3] + bb0.w, 0.0f);
        o1.x = fmaxf(di * acc[4] + bb1.x, 0.0f);
        o1.y = fmaxf(di * acc[5] + bb1.y, 0.0f);
        o1.z = fmaxf(di * acc[6] + bb1.z, 0.0f);
        o1.w = fmaxf(di * acc[7] + bb1.w, 0.0f);
        *(float4*)&xout[(size_t)i * H1 + sub * 8] = o0;
        *(float4*)&xout[(size_t)i * H1 + sub * 8 + 4] = o1;
    }
}

// ---------------------------------------------------------------- pull2: wave/node, 4 lanes/edge
__global__ __launch_bounds__(256) void pull2_kernel(const unsigned short* __restrict__ h,
                                                    const unsigned int* __restrict__ csr,
                                                    const int2* __restrict__ row_se,
                                                    const float* __restrict__ dinv,
                                                    const float* __restrict__ b,
                                                    float* __restrict__ xout) {
    int wave = (blockIdx.x * 256 + threadIdx.x) >> 6;
    int lane = threadIdx.x & 63;
    int g = lane >> 2;
    int sub = lane & 3;
    int i = wave;
    int2 se = row_se[i];
    int e0 = se.x, e1 = se.y;
    int deg = e1 - e0;
    const h2_t selo = {(_Float16)1.0f, (_Float16)0.0f};
    const h2_t sehi = {(_Float16)0.0f, (_Float16)1.0f};
    float acc[8] = {};
    if (deg <= 48) {
        int sidx = (int)csr[e0 + lane];
        int i0 = __shfl(sidx, g);
        int i1 = __shfl(sidx, 16 + g);
        int i2 = __shfl(sidx, 32 + g);
        bool p0 = (g < deg), p1 = (16 + g < deg), p2 = (32 + g < deg);
        uint4 v0 = make_uint4(0u, 0u, 0u, 0u), v1 = v0, v2 = v0;
        if (p0) v0 = *(const uint4*)&h[(size_t)i0 * H2 + sub * 8];
        if (p1) v1 = *(const uint4*)&h[(size_t)i1 * H2 + sub * 8];
        if (p2) v2 = *(const uint4*)&h[(size_t)i2 * H2 + sub * 8];
        if (p0) accd4(acc, v0, selo, sehi);
        if (p1) accd4(acc, v1, selo, sehi);
        if (p2) accd4(acc, v2, selo, sehi);
    } else {
        int e = e0;
        for (; e + 32 <= e1; e += 32) {
            int s0 = csr[e + g];
            int s1 = csr[e + 16 + g];
            uint4 v0 = *(const uint4*)&h[(size_t)s0 * H2 + sub * 8];
            uint4 v1 = *(const uint4*)&h[(size_t)s1 * H2 + sub * 8];
            accd4(acc, v0, selo, sehi);
            accd4(acc, v1, selo, sehi);
        }
        if (e + 16 <= e1) {
            int s = csr[e + g];
            uint4 v = *(const uint4*)&h[(size_t)s * H2 + sub * 8];
            accd4(acc, v, selo, sehi);
            e += 16;
        }
        if (e < e1) {
            int idx = e + g;
            if (idx < e1) {
                int s = csr[idx];
                uint4 v = *(const uint4*)&h[(size_t)s * H2 + sub * 8];
                accd4(acc, v, selo, sehi);
            }
        }
    }
    #pragma unroll
    for (int m = 4; m < 64; m <<= 1) {
        #pragma unroll
        for (int j = 0; j < 8; ++j) acc[j] += __shfl_xor(acc[j], m);
    }
    if (g == 0) {                       // lanes 0..3 finalize
        float di = dinv[i];
        uint4 sv = *(const uint4*)&h[(size_t)i * H2 + sub * 8];   // self loop
        accd4(acc, sv, selo, sehi);
        float4 bb0 = *(const float4*)&b[sub * 8];
        float4 bb1 = *(const float4*)&b[sub * 8 + 4];
        float4 o0, o1;
        o0.x = fmaxf(di * acc[0] + bb0.x, 0.0f);
        o0.y = fmaxf(di * acc[1] + bb0.y, 0.0f);
        o0.z = fmaxf(di * acc[2] + bb0.z, 0.0f);
        o0.w = fmaxf(di * acc[3] + bb0.w, 0.0f);
        o1.x = fmaxf(di * acc[4] + bb1.x, 0.0f);
        o1.y = fmaxf(di * acc[5] + bb1.y, 0.0f);
        o1.z = fmaxf(di * acc[6] + bb1.z, 0.0f);
        o1.w = fmaxf(di * acc[7] + bb1.w, 0.0f);
        *(float4*)&xout[(size_t)i * H2 + sub * 8] = o0;
        *(float4*)&xout[(size_t)i * H2 + sub * 8 + 4] = o1;
    }
}

// ---------------------------------------------------------------- classifier + log_softmax
__global__ __launch_bounds__(256) void final_kernel(const float* __restrict__ X2,
                                                    const float* __restrict__ Wc,
                                                    const float* __restrict__ bc,
                                                    float* __restrict__ out) {
    __shared__ float Ws[H2 * NCLS];   // 320 floats > 256 threads: loop
    __shared__ float bs[NCLS];
    for (int idx = threadIdx.x; idx < H2 * NCLS; idx += 256) Ws[idx] = Wc[idx];
    if (threadIdx.x < NCLS) bs[threadIdx.x] = bc[threadIdx.x];
    __syncthreads();
    int i = blockIdx.x * blockDim.x + threadIdx.x;
    if (i >= N_NODES) return;
    float x[H2];
    #pragma unroll
    for (int k = 0; k < H2; ++k) x[k] = X2[(size_t)i * H2 + k];
    float lg[NCLS];
    #pragma unroll
    for (int c = 0; c < NCLS; ++c) {
        float acc = bs[c];
        #pragma unroll
        for (int k = 0; k < H2; ++k) acc += x[k] * Ws[k * NCLS + c];
        lg[c] = acc;
    }
    float m = lg[0];
    #pragma unroll
    for (int c = 1; c < NCLS; ++c) m = fmaxf(m, lg[c]);
    float s = 0.0f;
    #pragma unroll
    for (int c = 0; c < NCLS; ++c) s += expf(lg[c] - m);
    float lse = m + logf(s);
    #pragma unroll
    for (int c = 0; c < NCLS; ++c) out[(size_t)i * NCLS + c] = lg[c] - lse;
}

// ----------------------------------------------------------------
extern "C" void kernel_launch(void* const* d_in, const int* in_sizes, int n_in,
                              void* d_out, int out_size, void* d_ws, size_t ws_size,
                              hipStream_t stream) {
    const float* feature = (const float*)d_in[0];
    const int*   eidx    = (const int*)d_in[1];
    const float* W1      = (const float*)d_in[2];
    const float* b1      = (const float*)d_in[3];
    const float* W2      = (const float*)d_in[4];
    const float* b2      = (const float*)d_in[5];
    const float* Wc      = (const float*)d_in[6];
    const float* bc      = (const float*)d_in[7];
    float* out = (float*)d_out;

    const int E = in_sizes[1] / 2;
    const int* src = eidx;
    const int* dst = eidx + E;

    float*          ws        = (float*)d_ws;
    float*          dinv      = ws;
    int2*           row_se    = (int2*)(dinv + N_NODES);
    unsigned int*   gcur      = (unsigned int*)(row_se + N_NODES);
    unsigned int*   ovcnt     = gcur + (size_t)NBUCK * 16;
    unsigned int*   ovbuf     = ovcnt + (size_t)NBUCK * 16;
    unsigned int*   mainr     = ovbuf + (size_t)NBUCK * OVCAP;
    unsigned short* h1b       = (unsigned short*)(mainr + (size_t)NBUCK * MCAP);
    float*          x1        = (float*)(h1b + (size_t)N_NODES * H1);
    unsigned short* h2b       = h1b;                 // overlay: h1 dead after pull1
    float*          x2        = x1;                  // overlay: x1 dead after gemm2

    // CSR build
    hipMemsetAsync(gcur, 0, (size_t)NBUCK * 32 * sizeof(unsigned int), stream);
    bin_kernel<<<BIN_WG, 512, 0, stream>>>(src, dst, E, gcur, mainr, ovcnt, ovbuf);
    build_kernel<<<NBUCK, 512, 0, stream>>>(gcur, mainr, ovcnt, ovbuf, dinv, row_se);

    // layer 1
    gemm1_kernel<<<(N_NODES + 63) / 64, 256, 0, stream>>>(feature, W1, dinv, h1b);
    {
        unsigned int grid = (unsigned int)(((size_t)N_NODES * 64 + 255) / 256);
        pull1_kernel<<<grid, 256, 0, stream>>>(h1b, mainr, row_se, dinv, b1, x1);
    }

    // layer 2
    gemm2_kernel<<<(N_NODES + 63) / 64, 256, 0, stream>>>(x1, W2, dinv, h2b);
    {
        unsigned int grid = (unsigned int)(((size_t)N_NODES * 64 + 255) / 256);
        pull2_kernel<<<grid, 256, 0, stream>>>(h2b, mainr, row_se, dinv, b2, x2);
    }

    // classifier + log_softmax
    final_kernel<<<(N_NODES + 255) / 256, 256, 0, stream>>>(x2, Wc, bc, out);
}

// Round 6
// 272.841 us; speedup vs baseline: 1.1701x; 1.0081x over previous
//
#include <hip/hip_runtime.h>

#define N_NODES 100000
#define F_IN 128
#define H1 64
#define H2 32
#define NCLS 10

#define BS_N 256                                   // nodes per bucket
#define NBUCK ((N_NODES + BS_N - 1) / BS_N)        // 391 buckets
#define LCAP 32                                    // LDS slots per bucket
#define MCAP 9216                                  // main entries per bucket (4-aligned fills)
#define OVCAP 6144                                 // overflow entries per bucket
#define STCAP 9216                                 // build LDS stage: mean 8192, +11 sigma
#define BIN_WG 256                                 // bin workgroups (1/CU), 512 thr each

typedef _Float16 h2_t __attribute__((ext_vector_type(2)));
typedef _Float16 f16x8 __attribute__((ext_vector_type(8)));
typedef float f32x4 __attribute__((ext_vector_type(4)));

// v_dot2_f32_f16: acc += pair.lo*sel.lo + pair.hi*sel.hi — 1 instr, no unpack
__device__ __forceinline__ float fdot2u(unsigned int u, h2_t sel, float c) {
    return __builtin_amdgcn_fdot2(__builtin_bit_cast(h2_t, u), sel, c, false);
}
// accumulate 8 packed fp16 (uint4) into a[0..7] with 8 dot2
__device__ __forceinline__ void accd4(float* a, uint4 v, h2_t lo, h2_t hi) {
    a[0] = fdot2u(v.x, lo, a[0]); a[1] = fdot2u(v.x, hi, a[1]);
    a[2] = fdot2u(v.y, lo, a[2]); a[3] = fdot2u(v.y, hi, a[3]);
    a[4] = fdot2u(v.z, lo, a[4]); a[5] = fdot2u(v.z, hi, a[5]);
    a[6] = fdot2u(v.w, lo, a[6]); a[7] = fdot2u(v.w, hi, a[7]);
}
// pack 2 f32 -> fp16x2 dword (v_cvt_pkrtz_f16_f32, 1 instr)
__device__ __forceinline__ unsigned int pkh(float a, float b) {
    return __builtin_bit_cast(unsigned int, __builtin_amdgcn_cvt_pkrtz(a, b));
}

// ---------------------------------------------------------------- pass 1: LDS-staged binning
// buf stride 33: bank=(b+k)%32 — flush reads (b=tid per lane, same k) hit
// consecutive banks instead of ALL lanes on bank k%32 (was 64-lane serialize).
// 2048 edges/iter halves barrier count; tail drains 4-aligned uint4 to mainr.
__global__ __launch_bounds__(512) void bin_kernel(const int* __restrict__ src,
                                                  const int* __restrict__ dst, int E,
                                                  unsigned int* __restrict__ gcur,
                                                  unsigned int* __restrict__ mainr,
                                                  unsigned int* __restrict__ ovcnt,
                                                  unsigned int* __restrict__ ovbuf) {
    __shared__ unsigned int buf[NBUCK][LCAP + 1];   // 51.6 KB, +1 pad
    __shared__ int cnt[NBUCK];
    int tid = threadIdx.x;
    for (int b = tid; b < NBUCK; b += 512) cnt[b] = 0;

    int chunk = (E + gridDim.x - 1) / gridDim.x;
    int e_lo = blockIdx.x * chunk;
    int e_hi = min(e_lo + chunk, E);

    int d[4], s[4];
    #pragma unroll
    for (int k = 0; k < 4; ++k) {
        int e = e_lo + k * 512 + tid;
        d[k] = 0; s[k] = 0;
        if (e < e_hi) { d[k] = dst[e]; s[k] = src[e]; }
    }
    __syncthreads();

    for (int base = e_lo; base < e_hi; base += 2048) {
        #pragma unroll
        for (int k = 0; k < 4; ++k) {
            if (base + k * 512 + tid < e_hi) {
                int b = d[k] >> 8;
                unsigned int en = ((unsigned int)s[k] << 8) | (unsigned int)(d[k] & 255);
                int p = atomicAdd(&cnt[b], 1);
                if (p < LCAP) buf[b][p] = en;
                else {
                    unsigned int op = atomicAdd(&ovcnt[b * 16], 1u);
                    if (op < OVCAP) ovbuf[(size_t)b * OVCAP + op] = en;
                }
            }
        }
        __syncthreads();
        {
            int nb = base + 2048;
            #pragma unroll
            for (int k = 0; k < 4; ++k) {
                int e = nb + k * 512 + tid;
                if (e < e_hi) { d[k] = dst[e]; s[k] = src[e]; }
            }
        }
        for (int b = tid; b < NBUCK; b += 512) {
            int c = cnt[b]; if (c > LCAP) c = LCAP;
            int nf = c & ~15;
            if (nf) {
                unsigned int gb = atomicAdd(&gcur[b * 16], (unsigned int)nf);
                if (gb + (unsigned)nf <= MCAP) {
                    for (int k = 0; k < nf; k += 4) {
                        uint4 v = make_uint4(buf[b][k], buf[b][k + 1],
                                             buf[b][k + 2], buf[b][k + 3]);
                        *(uint4*)&mainr[(size_t)b * MCAP + gb + k] = v;
                    }
                } else {
                    unsigned int op = atomicAdd(&ovcnt[b * 16], (unsigned int)nf);
                    for (int k = 0; k < nf; ++k)
                        if (op + k < OVCAP) ovbuf[(size_t)b * OVCAP + op + k] = buf[b][k];
                }
                int rem = c - nf;
                for (int k = 0; k < rem; ++k) buf[b][k] = buf[b][nf + k];
                cnt[b] = rem;
            } else {
                cnt[b] = c;
            }
        }
        __syncthreads();
    }
    // tail: flush multiples of 4 as uint4 to mainr (every gcur add is a multiple
    // of 4 -> gb always 4-aligned -> 16B-aligned store), residue <4 to ovbuf.
    for (int b = tid; b < NBUCK; b += 512) {
        int c = cnt[b]; if (c > LCAP) c = LCAP;
        int nf = c & ~3;
        if (nf) {
            unsigned int gb = atomicAdd(&gcur[b * 16], (unsigned int)nf);
            if (gb + (unsigned)nf <= MCAP) {
                for (int k = 0; k < nf; k += 4) {
                    uint4 v = make_uint4(buf[b][k], buf[b][k + 1],
                                         buf[b][k + 2], buf[b][k + 3]);
                    *(uint4*)&mainr[(size_t)b * MCAP + gb + k] = v;
                }
            } else {
                unsigned int op = atomicAdd(&ovcnt[b * 16], (unsigned int)nf);
                for (int k = 0; k < nf; ++k)
                    if (op + k < OVCAP) ovbuf[(size_t)b * OVCAP + op + k] = buf[b][k];
            }
        }
        int rem = c - nf;
        if (rem) {
            unsigned int ob = atomicAdd(&ovcnt[b * 16], (unsigned int)rem);
            for (int k = 0; k < rem; ++k)
                if (ob + k < OVCAP) ovbuf[(size_t)b * OVCAP + ob + k] = buf[b][nf + k];
        }
    }
}

// ---------------------------------------------------------------- pass 2: per-bucket local CSR build
// Permute into LDS, then coalesced block-copy to global.
__global__ __launch_bounds__(512) void build_kernel(const unsigned int* __restrict__ gcur,
                                                    unsigned int* __restrict__ mainr,
                                                    const unsigned int* __restrict__ ovcnt,
                                                    const unsigned int* __restrict__ ovbuf,
                                                    float* __restrict__ dinv,
                                                    int2* __restrict__ row_se) {
    __shared__ unsigned int stage[STCAP];   // 36 KB
    __shared__ unsigned int outb[STCAP];    // 36 KB — permuted entries staged in LDS
    __shared__ int degl[BS_N];
    __shared__ int rs_l[BS_N];
    __shared__ int curl[BS_N];
    __shared__ int wtot[4];
    int b = blockIdx.x;
    int tid = threadIdx.x;

    int cm = (int)gcur[b * 16]; if (cm > MCAP) cm = MCAP;
    for (int i = tid; i < cm; i += 512) stage[i] = mainr[(size_t)b * MCAP + i];
    int co = (int)ovcnt[b * 16]; if (co > OVCAP) co = OVCAP;
    for (int i = tid; i < co; i += 512) {
        int p = cm + i;
        if (p < STCAP) stage[p] = ovbuf[(size_t)b * OVCAP + i];
    }
    int c = cm + co; if (c > STCAP) c = STCAP;
    if (tid < BS_N) degl[tid] = 0;
    __syncthreads();

    for (int i = tid; i < c; i += 512) atomicAdd(&degl[stage[i] & 255], 1);
    __syncthreads();

    if (tid < BS_N) {                       // exclusive scan over 256 degrees (4 waves)
        int lane = tid & 63, w = tid >> 6;
        int d = degl[tid];
        int x = d;
        #pragma unroll
        for (int off = 1; off < 64; off <<= 1) {
            int y = __shfl_up(x, off);
            if (lane >= off) x += y;
        }
        if (lane == 63) wtot[w] = x;
        __syncthreads();
        int pbase = 0;
        #pragma unroll
        for (int k = 0; k < 4; ++k) if (k < w) pbase += wtot[k];
        rs_l[tid] = pbase + x - d;
        curl[tid] = 0;
    } else {
        __syncthreads();                    // match the scan's inner barrier
    }
    __syncthreads();

    // permute into LDS (scattered 4B LDS writes: cheap) ...
    for (int i = tid; i < c; i += 512) {
        unsigned int en = stage[i];
        int dl = en & 255;
        int p = atomicAdd(&curl[dl], 1);
        outb[rs_l[dl] + p] = en >> 8;
    }
    __syncthreads();
    // ... then stream to global coalesced (uint4); over-copy to c+3 is safe (<= MCAP region)
    size_t gbase = (size_t)b * MCAP;
    int c4 = (c + 3) >> 2;
    for (int i = tid; i < c4; i += 512)
        *(uint4*)&mainr[gbase + (size_t)i * 4] = *(const uint4*)&outb[i * 4];

    int node = b * BS_N + tid;
    if (tid < BS_N && node < N_NODES) {
        int deg = degl[tid];
        dinv[node] = rsqrtf((float)deg + 1.0f);
        int rs = (int)gbase + rs_l[tid];
        row_se[node] = make_int2(rs, rs + deg);
    }
}

// ---------------------------------------------------------------- GEMM 1: [N,128]@[128,64] -> fp16 (MFMA f16)
__global__ __launch_bounds__(256) void gemm1_kernel(const float* __restrict__ X,
                                                    const float* __restrict__ W,
                                                    const float* __restrict__ dinv,
                                                    unsigned short* __restrict__ H) {
    __shared__ union {
        struct {
            _Float16 As[64][136];   // +8 pad: frag ds_read_b128 lands 2-way max (free)
            _Float16 Wf[16][64][8]; // B-frag order: Wf[kgrp][col][j] = W[kgrp*8+j][col]
        } s;
        _Float16 Hs[64][72];        // epilogue staging (overlaps As; 72 for 16B-aligned rows)
    } u;
    int r0 = blockIdx.x * 64;
    int tid = threadIdx.x;
    // stage A: 64x128 f32 -> f16 (RNE via cast)
    for (int i = tid; i < 2048; i += 256) {
        int row = i >> 5, k4 = i & 31;
        int grow = r0 + row;
        float4 v = (grow < N_NODES) ? ((const float4*)X)[(size_t)grow * 32 + k4]
                                    : make_float4(0.f, 0.f, 0.f, 0.f);
        _Float16 t4[4] = {(_Float16)v.x, (_Float16)v.y, (_Float16)v.z, (_Float16)v.w};
        *(uint2*)&u.s.As[row][k4 * 4] = *(uint2*)t4;
    }
    // stage W in B-fragment order (8192 elems, once per block)
    for (int i = tid; i < F_IN * H1; i += 256) {
        int k = i >> 6, col = i & 63;
        u.s.Wf[k >> 3][col][k & 7] = (_Float16)W[i];
    }
    __syncthreads();

    int lane = tid & 63, w = tid >> 6;
    int lr = lane & 15, lkg = lane >> 4;
    f32x4 acc[4] = {{0.f, 0.f, 0.f, 0.f}, {0.f, 0.f, 0.f, 0.f},
                    {0.f, 0.f, 0.f, 0.f}, {0.f, 0.f, 0.f, 0.f}};
    #pragma unroll
    for (int ks = 0; ks < 4; ++ks) {
        f16x8 a = *(const f16x8*)&u.s.As[w * 16 + lr][ks * 32 + lkg * 8];
        #pragma unroll
        for (int nt = 0; nt < 4; ++nt) {
            f16x8 bfr = *(const f16x8*)&u.s.Wf[ks * 4 + lkg][nt * 16 + lr][0];
            acc[nt] = __builtin_amdgcn_mfma_f32_16x16x32_f16(a, bfr, acc[nt], 0, 0, 0);
        }
    }
    __syncthreads();            // all frag reads done before Hs overwrites As
    float dv[4];
    #pragma unroll
    for (int q = 0; q < 4; ++q) {
        int grow = r0 + w * 16 + lkg * 4 + q;
        dv[q] = (grow < N_NODES) ? dinv[grow] : 0.f;
    }
    #pragma unroll
    for (int nt = 0; nt < 4; ++nt)
        #pragma unroll
        for (int q = 0; q < 4; ++q)
            u.Hs[w * 16 + lkg * 4 + q][nt * 16 + lr] = (_Float16)(acc[nt][q] * dv[q]);
    __syncthreads();
    // cooperative coalesced store: 64 rows x 128B
    for (int i = tid; i < 512; i += 256) {
        int row = i >> 3, seg = i & 7;
        int grow = r0 + row;
        if (grow < N_NODES)
            *(uint4*)&H[(size_t)grow * H1 + seg * 8] = *(const uint4*)&u.Hs[row][seg * 8];
    }
}

// ---------------------------------------------------------------- GEMM 2: [N,64]@[64,32] -> fp16, scaled by dinv
__global__ __launch_bounds__(256) void gemm2_kernel(const float* __restrict__ X,
                                                    const float* __restrict__ W,
                                                    const float* __restrict__ dinv,
                                                    unsigned short* __restrict__ H) {
    __shared__ float Xs[64][68];
    __shared__ float Ws[H1 * H2];
    int r0 = blockIdx.x * 64;
    const float4* W4 = (const float4*)W;
    float4* Ws4 = (float4*)Ws;
    for (int i = threadIdx.x; i < H1 * H2 / 4; i += 256) Ws4[i] = W4[i];
    for (int it = 0; it < 4; ++it) {
        int idx = threadIdx.x + it * 256;
        int r = idx >> 4, k4 = idx & 15;
        int row = r0 + r;
        float4 v = (row < N_NODES)
            ? ((const float4*)X)[(size_t)row * 16 + k4]
            : make_float4(0.f, 0.f, 0.f, 0.f);
        *(float4*)&Xs[r][k4 * 4] = v;
    }
    __syncthreads();
    int tx = threadIdx.x & 15;
    int ty = threadIdx.x >> 4;
    float acc[4][2] = {};
    #pragma unroll 8
    for (int k = 0; k < 64; ++k) {
        float2 wb = *(const float2*)&Ws[k * H2 + tx * 2];
        float xa0 = Xs[ty * 4 + 0][k];
        float xa1 = Xs[ty * 4 + 1][k];
        float xa2 = Xs[ty * 4 + 2][k];
        float xa3 = Xs[ty * 4 + 3][k];
        acc[0][0] += xa0 * wb.x; acc[0][1] += xa0 * wb.y;
        acc[1][0] += xa1 * wb.x; acc[1][1] += xa1 * wb.y;
        acc[2][0] += xa2 * wb.x; acc[2][1] += xa2 * wb.y;
        acc[3][0] += xa3 * wb.x; acc[3][1] += xa3 * wb.y;
    }
    #pragma unroll
    for (int i = 0; i < 4; ++i) {
        int row = r0 + ty * 4 + i;
        if (row < N_NODES) {
            float dv = dinv[row];
            *(unsigned int*)&H[(size_t)row * H2 + tx * 2] = pkh(acc[i][0] * dv, acc[i][1] * dv);
        }
    }
}

// ---------------------------------------------------------------- pull1: wave/node, 8 lanes/edge
__global__ __launch_bounds__(256) void pull1_kernel(const unsigned short* __restrict__ h,
                                                    const unsigned int* __restrict__ csr,
                                                    const int2* __restrict__ row_se,
                                                    const float* __restrict__ dinv,
                                                    const float* __restrict__ b,
                                                    float* __restrict__ xout) {
    int wave = (blockIdx.x * 256 + threadIdx.x) >> 6;   // grid is exact: 25000 blocks
    int lane = threadIdx.x & 63;
    int g = lane >> 3;
    int sub = lane & 7;
    int i = wave;
    int2 se = row_se[i];
    int e0 = se.x, e1 = se.y;
    int deg = e1 - e0;
    const h2_t selo = {(_Float16)1.0f, (_Float16)0.0f};
    const h2_t sehi = {(_Float16)0.0f, (_Float16)1.0f};
    float acc[8] = {};
    if (deg <= 48) {                    // ~99.7% of nodes
        int sidx = (int)csr[e0 + lane];
        int i0 = __shfl(sidx, g);
        int i1 = __shfl(sidx, 8 + g);
        int i2 = __shfl(sidx, 16 + g);
        int i3 = __shfl(sidx, 24 + g);
        int i4 = __shfl(sidx, 32 + g);
        int i5 = __shfl(sidx, 40 + g);
        bool p0 = (g < deg),      p1 = (8 + g < deg),  p2 = (16 + g < deg);
        bool p3 = (24 + g < deg), p4 = (32 + g < deg), p5 = (40 + g < deg);
        uint4 v0 = make_uint4(0u, 0u, 0u, 0u), v1 = v0, v2 = v0, v3 = v0, v4 = v0, v5 = v0;
        if (p0) v0 = *(const uint4*)&h[(size_t)i0 * H1 + sub * 8];
        if (p1) v1 = *(const uint4*)&h[(size_t)i1 * H1 + sub * 8];
        if (p2) v2 = *(const uint4*)&h[(size_t)i2 * H1 + sub * 8];
        if (p3) v3 = *(const uint4*)&h[(size_t)i3 * H1 + sub * 8];
        if (p4) v4 = *(const uint4*)&h[(size_t)i4 * H1 + sub * 8];
        if (p5) v5 = *(const uint4*)&h[(size_t)i5 * H1 + sub * 8];
        if (p0) accd4(acc, v0, selo, sehi);
        if (p1) accd4(acc, v1, selo, sehi);
        if (p2) accd4(acc, v2, selo, sehi);
        if (p3) accd4(acc, v3, selo, sehi);
        if (p4) accd4(acc, v4, selo, sehi);
        if (p5) accd4(acc, v5, selo, sehi);
    } else {                            // rare heavy rows
        int e = e0;
        for (; e + 16 <= e1; e += 16) {
            int s0 = csr[e + g];
            int s1 = csr[e + 8 + g];
            uint4 v0 = *(const uint4*)&h[(size_t)s0 * H1 + sub * 8];
            uint4 v1 = *(const uint4*)&h[(size_t)s1 * H1 + sub * 8];
            accd4(acc, v0, selo, sehi);
            accd4(acc, v1, selo, sehi);
        }
        if (e + 8 <= e1) {
            int s = csr[e + g];
            uint4 v = *(const uint4*)&h[(size_t)s * H1 + sub * 8];
            accd4(acc, v, selo, sehi);
            e += 8;
        }
        if (e < e1) {
            int idx = e + g;
            if (idx < e1) {
                int s = csr[idx];
                uint4 v = *(const uint4*)&h[(size_t)s * H1 + sub * 8];
                accd4(acc, v, selo, sehi);
            }
        }
    }
    #pragma unroll
    for (int m = 8; m < 64; m <<= 1) {
        #pragma unroll
        for (int j = 0; j < 8; ++j) acc[j] += __shfl_xor(acc[j], m);
    }
    if (g == 0) {                       // lanes 0..7 finalize features sub*8..+7
        float di = dinv[i];
        uint4 sv = *(const uint4*)&h[(size_t)i * H1 + sub * 8];   // self loop
        accd4(acc, sv, selo, sehi);
        float4 bb0 = *(const float4*)&b[sub * 8];
        float4 bb1 = *(const float4*)&b[sub * 8 + 4];
        float4 o0, o1;
        o0.x = fmaxf(di * acc[0] + bb0.x, 0.0f);
        o0.y = fmaxf(di * acc[1] + bb0.y, 0.0f);
        o0.z = fmaxf(di * acc[2] + bb0.z, 0.0f);
        o0.w = fmaxf(di * acc[3] + bb0.w, 0.0f);
        o1.x = fmaxf(di * acc[4] + bb1.x, 0.0f);
        o1.y = fmaxf(di * acc[5] + bb1.y, 0.0f);
        o1.z = fmaxf(di * acc[6] + bb1.z, 0.0f);
        o1.w = fmaxf(di * acc[7] + bb1.w, 0.0f);
        *(float4*)&xout[(size_t)i * H1 + sub * 8] = o0;
        *(float4*)&xout[(size_t)i * H1 + sub * 8 + 4] = o1;
    }
}

// ---------------------------------------------------------------- pull2: wave/node, 4 lanes/edge
__global__ __launch_bounds__(256) void pull2_kernel(const unsigned short* __restrict__ h,
                                                    const unsigned int* __restrict__ csr,
                                                    const int2* __restrict__ row_se,
                                                    const float* __restrict__ dinv,
                                                    const float* __restrict__ b,
                                                    float* __restrict__ xout) {
    int wave = (blockIdx.x * 256 + threadIdx.x) >> 6;
    int lane = threadIdx.x & 63;
    int g = lane >> 2;
    int sub = lane & 3;
    int i = wave;
    int2 se = row_se[i];
    int e0 = se.x, e1 = se.y;
    int deg = e1 - e0;
    const h2_t selo = {(_Float16)1.0f, (_Float16)0.0f};
    const h2_t sehi = {(_Float16)0.0f, (_Float16)1.0f};
    float acc[8] = {};
    if (deg <= 48) {
        int sidx = (int)csr[e0 + lane];
        int i0 = __shfl(sidx, g);
        int i1 = __shfl(sidx, 16 + g);
        int i2 = __shfl(sidx, 32 + g);
        bool p0 = (g < deg), p1 = (16 + g < deg), p2 = (32 + g < deg);
        uint4 v0 = make_uint4(0u, 0u, 0u, 0u), v1 = v0, v2 = v0;
        if (p0) v0 = *(const uint4*)&h[(size_t)i0 * H2 + sub * 8];
        if (p1) v1 = *(const uint4*)&h[(size_t)i1 * H2 + sub * 8];
        if (p2) v2 = *(const uint4*)&h[(size_t)i2 * H2 + sub * 8];
        if (p0) accd4(acc, v0, selo, sehi);
        if (p1) accd4(acc, v1, selo, sehi);
        if (p2) accd4(acc, v2, selo, sehi);
    } else {
        int e = e0;
        for (; e + 32 <= e1; e += 32) {
            int s0 = csr[e + g];
            int s1 = csr[e + 16 + g];
            uint4 v0 = *(const uint4*)&h[(size_t)s0 * H2 + sub * 8];
            uint4 v1 = *(const uint4*)&h[(size_t)s1 * H2 + sub * 8];
            accd4(acc, v0, selo, sehi);
            accd4(acc, v1, selo, sehi);
        }
        if (e + 16 <= e1) {
            int s = csr[e + g];
            uint4 v = *(const uint4*)&h[(size_t)s * H2 + sub * 8];
            accd4(acc, v, selo, sehi);
            e += 16;
        }
        if (e < e1) {
            int idx = e + g;
            if (idx < e1) {
                int s = csr[idx];
                uint4 v = *(const uint4*)&h[(size_t)s * H2 + sub * 8];
                accd4(acc, v, selo, sehi);
            }
        }
    }
    #pragma unroll
    for (int m = 4; m < 64; m <<= 1) {
        #pragma unroll
        for (int j = 0; j < 8; ++j) acc[j] += __shfl_xor(acc[j], m);
    }
    if (g == 0) {                       // lanes 0..3 finalize
        float di = dinv[i];
        uint4 sv = *(const uint4*)&h[(size_t)i * H2 + sub * 8];   // self loop
        accd4(acc, sv, selo, sehi);
        float4 bb0 = *(const float4*)&b[sub * 8];
        float4 bb1 = *(const float4*)&b[sub * 8 + 4];
        float4 o0, o1;
        o0.x = fmaxf(di * acc[0] + bb0.x, 0.0f);
        o0.y = fmaxf(di * acc[1] + bb0.y, 0.0f);
        o0.z = fmaxf(di * acc[2] + bb0.z, 0.0f);
        o0.w = fmaxf(di * acc[3] + bb0.w, 0.0f);
        o1.x = fmaxf(di * acc[4] + bb1.x, 0.0f);
        o1.y = fmaxf(di * acc[5] + bb1.y, 0.0f);
        o1.z = fmaxf(di * acc[6] + bb1.z, 0.0f);
        o1.w = fmaxf(di * acc[7] + bb1.w, 0.0f);
        *(float4*)&xout[(size_t)i * H2 + sub * 8] = o0;
        *(float4*)&xout[(size_t)i * H2 + sub * 8 + 4] = o1;
    }
}

// ---------------------------------------------------------------- classifier + log_softmax
__global__ __launch_bounds__(256) void final_kernel(const float* __restrict__ X2,
                                                    const float* __restrict__ Wc,
                                                    const float* __restrict__ bc,
                                                    float* __restrict__ out) {
    __shared__ float Ws[H2 * NCLS];   // 320 floats > 256 threads: loop
    __shared__ float bs[NCLS];
    for (int idx = threadIdx.x; idx < H2 * NCLS; idx += 256) Ws[idx] = Wc[idx];
    if (threadIdx.x < NCLS) bs[threadIdx.x] = bc[threadIdx.x];
    __syncthreads();
    int i = blockIdx.x * blockDim.x + threadIdx.x;
    if (i >= N_NODES) return;
    float x[H2];
    #pragma unroll
    for (int k = 0; k < H2; ++k) x[k] = X2[(size_t)i * H2 + k];
    float lg[NCLS];
    #pragma unroll
    for (int c = 0; c < NCLS; ++c) {
        float acc = bs[c];
        #pragma unroll
        for (int k = 0; k < H2; ++k) acc += x[k] * Ws[k * NCLS + c];
        lg[c] = acc;
    }
    float m = lg[0];
    #pragma unroll
    for (int c = 1; c < NCLS; ++c) m = fmaxf(m, lg[c]);
    float s = 0.0f;
    #pragma unroll
    for (int c = 0; c < NCLS; ++c) s += expf(lg[c] - m);
    float lse = m + logf(s);
    #pragma unroll
    for (int c = 0; c < NCLS; ++c) out[(size_t)i * NCLS + c] = lg[c] - lse;
}

// ----------------------------------------------------------------
extern "C" void kernel_launch(void* const* d_in, const int* in_sizes, int n_in,
                              void* d_out, int out_size, void* d_ws, size_t ws_size,
                              hipStream_t stream) {
    const float* feature = (const float*)d_in[0];
    const int*   eidx    = (const int*)d_in[1];
    const float* W1      = (const float*)d_in[2];
    const float* b1      = (const float*)d_in[3];
    const float* W2      = (const float*)d_in[4];
    const float* b2      = (const float*)d_in[5];
    const float* Wc      = (const float*)d_in[6];
    const float* bc      = (const float*)d_in[7];
    float* out = (float*)d_out;

    const int E = in_sizes[1] / 2;
    const int* src = eidx;
    const int* dst = eidx + E;

    float*          ws        = (float*)d_ws;
    float*          dinv      = ws;
    int2*           row_se    = (int2*)(dinv + N_NODES);
    unsigned int*   gcur      = (unsigned int*)(row_se + N_NODES);
    unsigned int*   ovcnt     = gcur + (size_t)NBUCK * 16;
    unsigned int*   ovbuf     = ovcnt + (size_t)NBUCK * 16;
    unsigned int*   mainr     = ovbuf + (size_t)NBUCK * OVCAP;
    unsigned short* h1b       = (unsigned short*)(mainr + (size_t)NBUCK * MCAP);
    float*          x1        = (float*)(h1b + (size_t)N_NODES * H1);
    unsigned short* h2b       = h1b;                 // overlay: h1 dead after pull1
    float*          x2        = x1;                  // overlay: x1 dead after gemm2

    // CSR build
    hipMemsetAsync(gcur, 0, (size_t)NBUCK * 32 * sizeof(unsigned int), stream);
    bin_kernel<<<BIN_WG, 512, 0, stream>>>(src, dst, E, gcur, mainr, ovcnt, ovbuf);
    build_kernel<<<NBUCK, 512, 0, stream>>>(gcur, mainr, ovcnt, ovbuf, dinv, row_se);

    // layer 1
    gemm1_kernel<<<(N_NODES + 63) / 64, 256, 0, stream>>>(feature, W1, dinv, h1b);
    {
        unsigned int grid = (unsigned int)(((size_t)N_NODES * 64 + 255) / 256);
        pull1_kernel<<<grid, 256, 0, stream>>>(h1b, mainr, row_se, dinv, b1, x1);
    }

    // layer 2
    gemm2_kernel<<<(N_NODES + 63) / 64, 256, 0, stream>>>(x1, W2, dinv, h2b);
    {
        unsigned int grid = (unsigned int)(((size_t)N_NODES * 64 + 255) / 256);
        pull2_kernel<<<grid, 256, 0, stream>>>(h2b, mainr, row_se, dinv, b2, x2);
    }

    // classifier + log_softmax
    final_kernel<<<(N_NODES + 255) / 256, 256, 0, stream>>>(x2, Wc, bc, out);
}